// Round 14
// baseline (741.191 us; speedup 1.0000x reference)
//
#include <hip/hip_runtime.h>

#define NNODES 100000
#define NEDGES 600000
#define NGRAPH 64
#define HID 128
#define RHD 500
#define NB ((NNODES + 255) / 256)            // 391
#define EB ((NEDGES + 255) / 256)            // 2344
#define GG ((NNODES + 63) / 64)              // 1563 mfma gemm blocks

typedef __attribute__((ext_vector_type(8))) short short8;
typedef __attribute__((ext_vector_type(4))) float f32x4;

__device__ __forceinline__ float leaky1(float x) { return x >= 0.0f ? x : 0.01f * x; }

// fp32 -> bf16 hi + bf16 lo (round-to-nearest-even both)
__device__ __forceinline__ void splitf(float a, unsigned short& h, unsigned short& l)
{
    unsigned u = __float_as_uint(a);
    unsigned r = (u + 0x7FFFu + ((u >> 16) & 1u)) & 0xFFFF0000u;
    h = (unsigned short)(r >> 16);
    float res = a - __uint_as_float(r);
    unsigned u2 = __float_as_uint(res);
    l = (unsigned short)((u2 + 0x7FFFu + ((u2 >> 16) & 1u)) >> 16);
}

// ================= CSR build (deterministic) =================
__global__ __launch_bounds__(256) void hist_kernel(
    const int* __restrict__ ei, int* __restrict__ deg)
{
    int e = blockIdx.x * 256 + threadIdx.x;
    if (e < NEDGES) atomicAdd(&deg[ei[NEDGES + e]], 1);
}

__global__ __launch_bounds__(256) void scan_blk(
    const int* __restrict__ deg, int* __restrict__ incl, int* __restrict__ bsum)
{
    __shared__ int s[256];
    int t = threadIdx.x;
    int n = blockIdx.x * 256 + t;
    int v = (n < NNODES) ? deg[n] : 0;
    int x = v;
    s[t] = x;
    __syncthreads();
    for (int off = 1; off < 256; off <<= 1) {
        int y = (t >= off) ? s[t - off] : 0;
        __syncthreads();
        x += y; s[t] = x;
        __syncthreads();
    }
    if (n < NNODES) incl[n] = x;
    if (t == 255) bsum[blockIdx.x] = x;
}

__global__ __launch_bounds__(512) void scan_bsum(int* __restrict__ bsum, int nblk)
{
    __shared__ int s[512];
    int t = threadIdx.x;
    int v = (t < nblk) ? bsum[t] : 0;
    int x = v;
    s[t] = x;
    __syncthreads();
    for (int off = 1; off < 512; off <<= 1) {
        int y = (t >= off) ? s[t - off] : 0;
        __syncthreads();
        x += y; s[t] = x;
        __syncthreads();
    }
    if (t < nblk) bsum[t] = x - v;   // exclusive
}

__global__ __launch_bounds__(256) void finalize_rp(
    const int* __restrict__ deg, const int* __restrict__ bsum,
    int* __restrict__ rp, int* __restrict__ cursor)
{
    int n = blockIdx.x * 256 + threadIdx.x;
    if (n >= NNODES) return;
    int ig = rp[n] + bsum[blockIdx.x];   // global inclusive
    int st = ig - deg[n];
    rp[n] = st;
    cursor[n] = st;
    if (n == NNODES - 1) rp[NNODES] = ig;
}

__global__ __launch_bounds__(256) void scatter_kernel(
    const int* __restrict__ ei, int* __restrict__ cursor, int* __restrict__ eid)
{
    int e = blockIdx.x * 256 + threadIdx.x;
    if (e >= NEDGES) return;
    int d = ei[NEDGES + e];
    int pos = atomicAdd(&cursor[d], 1);
    eid[pos] = e;
}

__global__ __launch_bounds__(256) void seg_sort(
    const int* __restrict__ rp, int* __restrict__ eid)
{
    int n = blockIdx.x * 256 + threadIdx.x;
    if (n >= NNODES) return;
    int beg = rp[n], end = rp[n + 1];
    for (int i = beg + 1; i < end; ++i) {
        int key = eid[i];
        int j = i - 1;
        while (j >= beg && eid[j] > key) { eid[j + 1] = eid[j]; --j; }
        eid[j + 1] = key;
    }
}

__global__ __launch_bounds__(256) void permute_kernel(
    const int* __restrict__ eid, const int* __restrict__ ei,
    const float* __restrict__ ea, int* __restrict__ srcp, float* __restrict__ eap)
{
    int p = blockIdx.x * 256 + threadIdx.x;
    if (p >= NEDGES) return;
    int id = eid[p];
    srcp[p] = ei[id];
    const float* s = ea + (size_t)id * 7;
    float* d = eap + (size_t)p * 7;
#pragma unroll
    for (int k = 0; k < 7; ++k) d[k] = s[k];
}

// ================= W split: 7 fp32 [128][128] -> bf16 hi/lo, one launch =================
__global__ __launch_bounds__(256) void wsplit_all(
    const float* __restrict__ w20, const float* __restrict__ w1S,
    const float* __restrict__ w2S,
    unsigned short* __restrict__ wh, unsigned short* __restrict__ wl)
{
    int i = blockIdx.x * 256 + threadIdx.x;   // 7*16384 = 114688
    int m = i >> 14;
    int off = i & 16383;
    const float* src;
    if (m == 0) src = w20;
    else if (m <= 3) src = w1S + (size_t)(m - 1) * 16384;
    else src = w2S + (size_t)(m - 4) * 16384;
    unsigned short h, l;
    splitf(src[off], h, l);
    wh[i] = h;
    wl[i] = l;
}

// ================= layer 0 aggregate (d=2) =================
__global__ __launch_bounds__(256) void aggregate0_kernel(
    const float* __restrict__ x, const int* __restrict__ rp,
    const int* __restrict__ srcp, const float* __restrict__ eap,
    const float* __restrict__ ew, const float* __restrict__ eb,
    float* __restrict__ aggr2)
{
    int n = blockIdx.x * 256 + threadIdx.x;
    if (n >= NNODES) return;
    float w0[7], w1[7];
#pragma unroll
    for (int k = 0; k < 7; ++k) { w0[k] = ew[k]; w1[k] = ew[7 + k]; }
    float e0b = eb[0], e1b = eb[1];
    float a0 = x[n * 2 + 0], a1 = x[n * 2 + 1];
    int beg = rp[n], end = rp[n + 1];
    for (int e = beg; e < end; ++e) {
        int s = srcp[e];
        const float* ap = eap + (size_t)e * 7;
        float t0 = e0b, t1 = e1b;
#pragma unroll
        for (int k = 0; k < 7; ++k) {
            float av = ap[k];
            t0 = fmaf(av, w0[k], t0);
            t1 = fmaf(av, w1[k], t1);
        }
        a0 += fmaxf(x[s * 2 + 0] + t0, 0.0f);
        a1 += fmaxf(x[s * 2 + 1] + t1, 0.0f);
    }
    aggr2[n * 2 + 0] = a0;
    aggr2[n * 2 + 1] = a1;
}

// ================= hidden aggregate: streaming segmented reduction =================
// Wave = 8 nodes x 64 channels (halves split across waves -> 2x waves, 1 gather/edge).
// The 8 nodes' edges are one contiguous CSR span: 4-deep pipeline runs full-rate
// across node boundaries; boundary handling is a wave-uniform while (edge order
// preserved -> deterministic, bitwise-identical sums).
__global__ __launch_bounds__(256) void aggregate_kernel(
    const float* __restrict__ hin, const int* __restrict__ rp,
    const int* __restrict__ srcp, const float* __restrict__ eap,
    const float* __restrict__ ew, const float* __restrict__ eb,
    unsigned short* __restrict__ Ahi, unsigned short* __restrict__ Alo)
{
    const int lane = threadIdx.x & 63;
    const int w = threadIdx.x >> 6;
    const int grp = w >> 1, half = w & 1;
    const int nbase = blockIdx.x * 16 + grp * 8;
    const int nend = nbase + 8;
    const int c = half * 64 + lane;

    float ewv[7];
#pragma unroll
    for (int k = 0; k < 7; ++k) ewv[k] = ew[c * 7 + k];
    const float ebv = eb[c];

    int n = nbase;
    int e = rp[nbase];
    const int eend = rp[nend];
    int next = rp[n + 1];
    float a = hin[(size_t)n * HID + c];

#define EMIT_ADVANCE() { \
        unsigned short hh, ll; splitf(a, hh, ll); \
        size_t rb = (size_t)n * HID + c; \
        Ahi[rb] = hh; Alo[rb] = ll; \
        ++n; a = hin[(size_t)n * HID + c]; next = rp[n + 1]; }

    while (e + 4 <= eend) {
        int s0 = srcp[e], s1 = srcp[e + 1], s2 = srcp[e + 2], s3 = srcp[e + 3];
        const float* ap = eap + (size_t)e * 7;
        float x0 = hin[(size_t)s0 * HID + c];
        float x1 = hin[(size_t)s1 * HID + c];
        float x2 = hin[(size_t)s2 * HID + c];
        float x3 = hin[(size_t)s3 * HID + c];
        float t0 = ebv, t1 = ebv, t2 = ebv, t3 = ebv;
#pragma unroll
        for (int k = 0; k < 7; ++k) {
            t0 = fmaf(ap[k],      ewv[k], t0);
            t1 = fmaf(ap[7 + k],  ewv[k], t1);
            t2 = fmaf(ap[14 + k], ewv[k], t2);
            t3 = fmaf(ap[21 + k], ewv[k], t3);
        }
        float m0 = fmaxf(x0 + t0, 0.0f);
        float m1 = fmaxf(x1 + t1, 0.0f);
        float m2 = fmaxf(x2 + t2, 0.0f);
        float m3 = fmaxf(x3 + t3, 0.0f);
        while (e >= next)     EMIT_ADVANCE();
        a += m0;
        while (e + 1 >= next) EMIT_ADVANCE();
        a += m1;
        while (e + 2 >= next) EMIT_ADVANCE();
        a += m2;
        while (e + 3 >= next) EMIT_ADVANCE();
        a += m3;
        e += 4;
    }
    for (; e < eend; ++e) {
        int s = srcp[e];
        const float* ap = eap + (size_t)e * 7;
        float xv = hin[(size_t)s * HID + c];
        float t = ebv;
#pragma unroll
        for (int k = 0; k < 7; ++k) t = fmaf(ap[k], ewv[k], t);
        while (e >= next) EMIT_ADVANCE();
        a += fmaxf(xv + t, 0.0f);
    }
#undef EMIT_ADVANCE
    // flush remaining nodes (also handles trailing zero-degree nodes)
    while (n < nend) {
        unsigned short hh, ll;
        splitf(a, hh, ll);
        size_t rb = (size_t)n * HID + c;
        Ahi[rb] = hh; Alo[rb] = ll;
        ++n;
        if (n < nend) {
            a = hin[(size_t)n * HID + c];
            next = rp[n + 1];
        }
    }
}

// ================= layer 0 GEMM1 (in=2 -> 128) =================
__global__ __launch_bounds__(256) void gemm1_l0_kernel(
    const float* __restrict__ aggr2,
    const float* __restrict__ w1, const float* __restrict__ b1,
    float* __restrict__ h1)
{
    int n = blockIdx.x * 256 + threadIdx.x;
    if (n >= NNODES) return;
    float x0 = aggr2[n * 2 + 0];
    float x1 = aggr2[n * 2 + 1];
    float4* out4 = (float4*)(h1 + (size_t)n * HID);
    for (int j = 0; j < HID; j += 4) {
        float4 o;
        o.x = fmaf(x1, w1[(j + 0) * 2 + 1], fmaf(x0, w1[(j + 0) * 2 + 0], b1[j + 0]));
        o.y = fmaf(x1, w1[(j + 1) * 2 + 1], fmaf(x0, w1[(j + 1) * 2 + 0], b1[j + 1]));
        o.z = fmaf(x1, w1[(j + 2) * 2 + 1], fmaf(x0, w1[(j + 2) * 2 + 0], b1[j + 2]));
        o.w = fmaf(x1, w1[(j + 3) * 2 + 1], fmaf(x0, w1[(j + 3) * 2 + 0], b1[j + 3]));
        out4[j >> 2] = o;
    }
}

// ================= BN partial stats (layer 0 only) =================
__global__ __launch_bounds__(256) void bn_stats_part(
    const float* __restrict__ h1, float* __restrict__ part)
{
    __shared__ float ls[HID], lq[HID];
    int c = threadIdx.x & 127;
    int half = threadIdx.x >> 7;
    int base = blockIdx.x * 256;
    int end = base + 256; if (end > NNODES) end = NNODES;
    float s = 0.0f, q = 0.0f;
    for (int r = base + half; r < end; r += 2) {
        float v = h1[(size_t)r * HID + c];
        s += v;
        q = fmaf(v, v, q);
    }
    if (half) { ls[c] = s; lq[c] = q; }
    __syncthreads();
    if (!half) {
        s += ls[c]; q += lq[c];
        part[(size_t)blockIdx.x * 256 + c] = s;
        part[(size_t)blockIdx.x * 256 + 128 + c] = q;
    }
}

// ================= BN finalize -> scale/shift (256 thr/block, HID blocks) =================
__global__ __launch_bounds__(256) void bn_finalize(
    const float* __restrict__ part, int nblk,
    const float* __restrict__ gamma, const float* __restrict__ beta,
    float* __restrict__ scsh)
{
    __shared__ float ls[256], lq[256];
    int c = blockIdx.x;            // 0..127
    int t = threadIdx.x;
    float s = 0.0f, q = 0.0f;
    for (int i = t; i < nblk; i += 256) {
        s += part[(size_t)i * 256 + c];
        q += part[(size_t)i * 256 + 128 + c];
    }
    ls[t] = s; lq[t] = q;
    __syncthreads();
#pragma unroll
    for (int off = 128; off >= 1; off >>= 1) {
        if (t < off) { ls[t] += ls[t + off]; lq[t] += lq[t + off]; }
        __syncthreads();
    }
    if (t == 0) {
        const float invN = 1.0f / (float)NNODES;
        float mu = ls[0] * invN;
        float var = fmaf(-mu, mu, lq[0] * invN);
        float iv = rsqrtf(var + 1e-5f);
        float sc = gamma[c] * iv;
        scsh[c] = sc;
        scsh[HID + c] = beta[c] - mu * sc;
    }
}

// ================= GEMM1 (LDS-staged bf16 pair): h1 = A @ W1^T + b1 + BN partials =================
__global__ __launch_bounds__(256) void gemm1_lds(
    const unsigned short* __restrict__ Ahi, const unsigned short* __restrict__ Alo,
    const unsigned short* __restrict__ wh, const unsigned short* __restrict__ wl,
    const float* __restrict__ b1, float* __restrict__ h1,
    float* __restrict__ part)
{
    __shared__ __align__(16) short lds[16384];   // 32KB: hi [0,16KB), lo [16KB,32KB)
    const int t = threadIdx.x;
    const int mb = blockIdx.x * 64;

#pragma unroll
    for (int u = 0; u < 4; ++u) {
        int idx = u * 256 + t;
        int row = idx >> 4, sl = idx & 15;
        int gr = mb + row;
        short8 hv, lv;
#pragma unroll
        for (int e = 0; e < 8; ++e) { hv[e] = 0; lv[e] = 0; }
        if (gr < NNODES) {
            hv = *(const short8*)(Ahi + (size_t)gr * HID + sl * 8);
            lv = *(const short8*)(Alo + (size_t)gr * HID + sl * 8);
        }
        int byt = row * 256 + ((sl ^ (row & 7)) << 4);
        *(short8*)((char*)lds + byt) = hv;
        *(short8*)((char*)lds + 16384 + byt) = lv;
    }
    __syncthreads();

    const int lane = t & 63;
    const int wv = t >> 6;
    const int cl = lane & 15, g = lane >> 4, x = lane & 7;
    const int colbase = wv * 32;

    int aoff[4];
#pragma unroll
    for (int ks = 0; ks < 4; ++ks)
        aoff[ks] = cl * 256 + (((ks * 4 + g) ^ x) << 4);

    const unsigned short* wb_h0 = wh + (size_t)(colbase + cl) * HID + g * 8;
    const unsigned short* wb_h1 = wb_h0 + 16 * HID;
    const unsigned short* wb_l0 = wl + (size_t)(colbase + cl) * HID + g * 8;
    const unsigned short* wb_l1 = wb_l0 + 16 * HID;

    f32x4 acc[4][2];
#pragma unroll
    for (int rt = 0; rt < 4; ++rt) {
        acc[rt][0] = (f32x4){0.f, 0.f, 0.f, 0.f};
        acc[rt][1] = (f32x4){0.f, 0.f, 0.f, 0.f};
    }

#pragma unroll
    for (int ks = 0; ks < 4; ++ks) {
        short8 bh0 = *(const short8*)(wb_h0 + ks * 32);
        short8 bh1 = *(const short8*)(wb_h1 + ks * 32);
        short8 bl0 = *(const short8*)(wb_l0 + ks * 32);
        short8 bl1 = *(const short8*)(wb_l1 + ks * 32);
#pragma unroll
        for (int rt = 0; rt < 4; ++rt) {
            short8 ah = *(const short8*)((const char*)lds + (rt * 4096) + aoff[ks]);
            short8 al = *(const short8*)((const char*)lds + (16384 + rt * 4096) + aoff[ks]);
            acc[rt][0] = __builtin_amdgcn_mfma_f32_16x16x32_bf16(ah, bh0, acc[rt][0], 0, 0, 0);
            acc[rt][1] = __builtin_amdgcn_mfma_f32_16x16x32_bf16(ah, bh1, acc[rt][1], 0, 0, 0);
            acc[rt][0] = __builtin_amdgcn_mfma_f32_16x16x32_bf16(al, bh0, acc[rt][0], 0, 0, 0);
            acc[rt][1] = __builtin_amdgcn_mfma_f32_16x16x32_bf16(al, bh1, acc[rt][1], 0, 0, 0);
            acc[rt][0] = __builtin_amdgcn_mfma_f32_16x16x32_bf16(ah, bl0, acc[rt][0], 0, 0, 0);
            acc[rt][1] = __builtin_amdgcn_mfma_f32_16x16x32_bf16(ah, bl1, acc[rt][1], 0, 0, 0);
        }
    }

    float bj0 = b1[colbase + cl];
    float bj1 = b1[colbase + 16 + cl];
    float s0 = 0.f, q0 = 0.f, s1 = 0.f, q1 = 0.f;
#pragma unroll
    for (int rt = 0; rt < 4; ++rt) {
        int rbase = mb + rt * 16 + g * 4;
#pragma unroll
        for (int r = 0; r < 4; ++r) {
            int grow = rbase + r;
            if (grow < NNODES) {
                float o0 = acc[rt][0][r] + bj0;
                float o1 = acc[rt][1][r] + bj1;
                h1[(size_t)grow * HID + colbase + cl] = o0;
                h1[(size_t)grow * HID + colbase + 16 + cl] = o1;
                s0 += o0; q0 = fmaf(o0, o0, q0);
                s1 += o1; q1 = fmaf(o1, o1, q1);
            }
        }
    }
    __syncthreads();                 // LDS frag reads done; reuse as scratch
    float* red = (float*)lds;        // 1024 floats
    red[(colbase + cl) * 4 + g] = s0;
    red[(colbase + 16 + cl) * 4 + g] = s1;
    red[512 + (colbase + cl) * 4 + g] = q0;
    red[512 + (colbase + 16 + cl) * 4 + g] = q1;
    __syncthreads();
    {
        int stat = t >> 7, col = t & 127;
        const float* bp = red + stat * 512 + col * 4;
        part[(size_t)blockIdx.x * 256 + stat * 128 + col] = bp[0] + bp[1] + bp[2] + bp[3];
    }
}

// ================= MFMA GEMM2: Hout = leaky(leaky( leaky(BN(Ain)) @ W^T + b )) =================
template<int PRE, int POST>
__global__ __launch_bounds__(256) void gemm_mfma(
    const float* __restrict__ Ain, const float* __restrict__ scsh,
    const unsigned short* __restrict__ wh, const unsigned short* __restrict__ wl,
    const float* __restrict__ bias, float* __restrict__ Hout)
{
    __shared__ __align__(16) short lds[16384];   // 32KB
    const int t = threadIdx.x;
    const int mb = blockIdx.x * 64;

    const float4* sc4 = (const float4*)scsh;
    const float4* sh4 = (const float4*)(scsh + HID);

#pragma unroll
    for (int u = 0; u < 4; ++u) {
        int idx = u * 256 + t;
        int row = idx >> 4, sl = idx & 15;
        float4 v0 = make_float4(0.f, 0.f, 0.f, 0.f);
        float4 v1 = make_float4(0.f, 0.f, 0.f, 0.f);
        int gr = mb + row;
        if (gr < NNODES) {
            const float4* p = (const float4*)(Ain + (size_t)gr * HID + sl * 8);
            v0 = p[0]; v1 = p[1];
            if (PRE) {
                float4 c0 = sc4[sl * 2], c1 = sc4[sl * 2 + 1];
                float4 s0 = sh4[sl * 2], s1 = sh4[sl * 2 + 1];
                v0.x = leaky1(fmaf(v0.x, c0.x, s0.x));
                v0.y = leaky1(fmaf(v0.y, c0.y, s0.y));
                v0.z = leaky1(fmaf(v0.z, c0.z, s0.z));
                v0.w = leaky1(fmaf(v0.w, c0.w, s0.w));
                v1.x = leaky1(fmaf(v1.x, c1.x, s1.x));
                v1.y = leaky1(fmaf(v1.y, c1.y, s1.y));
                v1.z = leaky1(fmaf(v1.z, c1.z, s1.z));
                v1.w = leaky1(fmaf(v1.w, c1.w, s1.w));
            }
        }
        unsigned short h[8], l[8];
        splitf(v0.x, h[0], l[0]); splitf(v0.y, h[1], l[1]);
        splitf(v0.z, h[2], l[2]); splitf(v0.w, h[3], l[3]);
        splitf(v1.x, h[4], l[4]); splitf(v1.y, h[5], l[5]);
        splitf(v1.z, h[6], l[6]); splitf(v1.w, h[7], l[7]);
        short8 hv, lv;
#pragma unroll
        for (int e = 0; e < 8; ++e) { hv[e] = (short)h[e]; lv[e] = (short)l[e]; }
        int byt = row * 256 + ((sl ^ (row & 7)) << 4);
        *(short8*)((char*)lds + byt) = hv;
        *(short8*)((char*)lds + 16384 + byt) = lv;
    }
    __syncthreads();

    const int lane = t & 63;
    const int wv = t >> 6;
    const int cl = lane & 15, g = lane >> 4, x = lane & 7;
    const int colbase = wv * 32;

    int aoff[4];
#pragma unroll
    for (int ks = 0; ks < 4; ++ks)
        aoff[ks] = cl * 256 + (((ks * 4 + g) ^ x) << 4);

    const unsigned short* wb_h0 = wh + (size_t)(colbase + cl) * HID + g * 8;
    const unsigned short* wb_h1 = wb_h0 + 16 * HID;
    const unsigned short* wb_l0 = wl + (size_t)(colbase + cl) * HID + g * 8;
    const unsigned short* wb_l1 = wb_l0 + 16 * HID;

    f32x4 acc[4][2];
#pragma unroll
    for (int rt = 0; rt < 4; ++rt) {
        acc[rt][0] = (f32x4){0.f, 0.f, 0.f, 0.f};
        acc[rt][1] = (f32x4){0.f, 0.f, 0.f, 0.f};
    }

#pragma unroll
    for (int ks = 0; ks < 4; ++ks) {
        short8 bh0 = *(const short8*)(wb_h0 + ks * 32);
        short8 bh1 = *(const short8*)(wb_h1 + ks * 32);
        short8 bl0 = *(const short8*)(wb_l0 + ks * 32);
        short8 bl1 = *(const short8*)(wb_l1 + ks * 32);
#pragma unroll
        for (int rt = 0; rt < 4; ++rt) {
            short8 ah = *(const short8*)((const char*)lds + (rt * 4096) + aoff[ks]);
            short8 al = *(const short8*)((const char*)lds + (16384 + rt * 4096) + aoff[ks]);
            acc[rt][0] = __builtin_amdgcn_mfma_f32_16x16x32_bf16(ah, bh0, acc[rt][0], 0, 0, 0);
            acc[rt][1] = __builtin_amdgcn_mfma_f32_16x16x32_bf16(ah, bh1, acc[rt][1], 0, 0, 0);
            acc[rt][0] = __builtin_amdgcn_mfma_f32_16x16x32_bf16(al, bh0, acc[rt][0], 0, 0, 0);
            acc[rt][1] = __builtin_amdgcn_mfma_f32_16x16x32_bf16(al, bh1, acc[rt][1], 0, 0, 0);
            acc[rt][0] = __builtin_amdgcn_mfma_f32_16x16x32_bf16(ah, bl0, acc[rt][0], 0, 0, 0);
            acc[rt][1] = __builtin_amdgcn_mfma_f32_16x16x32_bf16(ah, bl1, acc[rt][1], 0, 0, 0);
        }
    }

    float bj0 = bias[colbase + cl];
    float bj1 = bias[colbase + 16 + cl];
#pragma unroll
    for (int rt = 0; rt < 4; ++rt) {
        int rbase = mb + rt * 16 + g * 4;
#pragma unroll
        for (int r = 0; r < 4; ++r) {
            int grow = rbase + r;
            if (grow < NNODES) {
                float o0 = acc[rt][0][r] + bj0;
                float o1 = acc[rt][1][r] + bj1;
                if (POST) { o0 = leaky1(leaky1(o0)); o1 = leaky1(leaky1(o1)); }
                Hout[(size_t)grow * HID + colbase + cl] = o0;
                Hout[(size_t)grow * HID + colbase + 16 + cl] = o1;
            }
        }
    }
}

// ================= global mean pool (batch sorted) =================
__global__ __launch_bounds__(256) void pool_kernel(
    const float* __restrict__ h, const int* __restrict__ batch,
    float* __restrict__ sums, float* __restrict__ cnt)
{
    int c = threadIdx.x & 127;
    int half = threadIdx.x >> 7;
    int base = blockIdx.x * 128 + half * 64;
    if (base >= NNODES) return;
    int end = base + 64; if (end > NNODES) end = NNODES;
    int g = batch[base];
    float acc = 0.0f, k = 0.0f;
    for (int n = base; n < end; ++n) {
        int gn = batch[n];
        if (gn != g) {
            atomicAdd(&sums[g * HID + c], acc);
            if (c == 0) atomicAdd(&cnt[g], k);
            acc = 0.0f; k = 0.0f; g = gn;
        }
        acc += h[(size_t)n * HID + c];
        k += 1.0f;
    }
    atomicAdd(&sums[g * HID + c], acc);
    if (c == 0) atomicAdd(&cnt[g], k);
}

// ================= reghead =================
__global__ __launch_bounds__(512) void reghead_kernel(
    const float* __restrict__ sums, const float* __restrict__ cnt,
    const float* __restrict__ wr, const float* __restrict__ br,
    const float* __restrict__ we, const float* __restrict__ be,
    float* __restrict__ out)
{
    __shared__ float pool[8 * HID];
    __shared__ float red[8][8];
    int g0 = blockIdx.x * 8;
    for (int i = threadIdx.x; i < 8 * HID; i += 512) {
        int g = g0 + (i >> 7);
        float c = cnt[g]; c = fmaxf(c, 1.0f);
        pool[i] = sums[g * HID + (i & 127)] / c;
    }
    __syncthreads();
    int j = threadIdx.x;
    float p[8];
#pragma unroll
    for (int g = 0; g < 8; ++g) p[g] = 0.0f;
    if (j < RHD) {
        float accs[8];
        float bjv = br[j];
#pragma unroll
        for (int g = 0; g < 8; ++g) accs[g] = bjv;
        const float4* wr4 = (const float4*)(wr + (size_t)j * HID);
        const float4* pool4 = (const float4*)pool;
        for (int k = 0; k < 32; ++k) {
            float4 w = wr4[k];
#pragma unroll
            for (int g = 0; g < 8; ++g) {
                float4 pv = pool4[g * 32 + k];
                accs[g] = fmaf(w.x, pv.x, accs[g]);
                accs[g] = fmaf(w.y, pv.y, accs[g]);
                accs[g] = fmaf(w.z, pv.z, accs[g]);
                accs[g] = fmaf(w.w, pv.w, accs[g]);
            }
        }
        float wej = we[j];
#pragma unroll
        for (int g = 0; g < 8; ++g) p[g] = leaky1(accs[g]) * wej;
    }
    int lane = threadIdx.x & 63, wid = threadIdx.x >> 6;
#pragma unroll
    for (int g = 0; g < 8; ++g) {
        float v = p[g];
        v += __shfl_down(v, 32); v += __shfl_down(v, 16); v += __shfl_down(v, 8);
        v += __shfl_down(v, 4);  v += __shfl_down(v, 2);  v += __shfl_down(v, 1);
        if (lane == 0) red[g][wid] = v;
    }
    __syncthreads();
    if (threadIdx.x < 8) {
        float sv = be[0];
#pragma unroll
        for (int w = 0; w < 8; ++w) sv += red[threadIdx.x][w];
        out[g0 + threadIdx.x] = sv;
    }
}

extern "C" void kernel_launch(void* const* d_in, const int* in_sizes, int n_in,
                              void* d_out, int out_size, void* d_ws, size_t ws_size,
                              hipStream_t stream)
{
    const float* x     = (const float*)d_in[0];
    const int*   ei    = (const int*)d_in[1];
    const int*   batch = (const int*)d_in[2];
    const float* ea    = (const float*)d_in[3];
    const float* ew0   = (const float*)d_in[4];
    const float* eb0   = (const float*)d_in[5];
    const float* w10   = (const float*)d_in[6];
    const float* b10   = (const float*)d_in[7];
    const float* g0v   = (const float*)d_in[8];
    const float* be0   = (const float*)d_in[9];
    const float* w20   = (const float*)d_in[10];
    const float* b20   = (const float*)d_in[11];
    const float* ewS   = (const float*)d_in[12];
    const float* ebS   = (const float*)d_in[13];
    const float* w1S   = (const float*)d_in[14];
    const float* b1S   = (const float*)d_in[15];
    const float* gS    = (const float*)d_in[16];
    const float* beS   = (const float*)d_in[17];
    const float* w2S   = (const float*)d_in[18];
    const float* b2S   = (const float*)d_in[19];
    const float* wr    = (const float*)d_in[20];
    const float* br    = (const float*)d_in[21];
    const float* we    = (const float*)d_in[22];
    const float* be_   = (const float*)d_in[23];

    float* ws    = (float*)d_ws;
    float* buf0  = ws;                                   // N*128 (h1)
    float* buf1  = buf0 + (size_t)NNODES * HID;          // N*128 (h)
    float* buf2  = buf1 + (size_t)NNODES * HID;          // N*128 (Ahi/Alo bf16 pair)
    unsigned short* Ahi = (unsigned short*)buf2;         // N*128 bf16
    unsigned short* Alo = Ahi + (size_t)NNODES * HID;    // N*128 bf16
    float* part  = buf2 + (size_t)NNODES * HID;          // GG*256
    float* scsh  = part + (size_t)GG * 256;              // 256
    float* sums  = scsh + 256;                           // 64*128
    float* cnt   = sums + NGRAPH * HID;                  // 64
    float* aggr2 = cnt + NGRAPH;                         // N*2
    float* eap   = aggr2 + (size_t)NNODES * 2;           // E*7
    int*   deg    = (int*)(eap + (size_t)NEDGES * 7);    // N
    int*   cursor = deg + NNODES;                        // N
    int*   bsum   = cursor + NNODES;                     // 512
    int*   rp     = bsum + 512;                          // N+1
    int*   eid    = rp + NNODES + 1;                     // E
    int*   srcp   = eid + NEDGES;                        // E
    unsigned short* whA = (unsigned short*)(srcp + NEDGES);  // 7*16384
    unsigned short* wlA = whA + 7 * 16384;                   // 7*16384
    float* out   = (float*)d_out;

    // ---- CSR build (deterministic; once per launch) ----
    hipMemsetAsync(deg, 0, (size_t)NNODES * sizeof(int), stream);
    hist_kernel<<<EB, 256, 0, stream>>>(ei, deg);
    scan_blk<<<NB, 256, 0, stream>>>(deg, rp, bsum);
    scan_bsum<<<1, 512, 0, stream>>>(bsum, NB);
    finalize_rp<<<NB, 256, 0, stream>>>(deg, bsum, rp, cursor);
    scatter_kernel<<<EB, 256, 0, stream>>>(ei, cursor, eid);
    seg_sort<<<NB, 256, 0, stream>>>(rp, eid);
    permute_kernel<<<EB, 256, 0, stream>>>(eid, ei, ea, srcp, eap);

    // ---- weight split: one launch ----
    wsplit_all<<<448, 256, 0, stream>>>(w20, w1S, w2S, whA, wlA);

    // ---- layer 0: h1 -> buf0, h -> buf1 ----
    aggregate0_kernel<<<NB, 256, 0, stream>>>(x, rp, srcp, eap, ew0, eb0, aggr2);
    gemm1_l0_kernel<<<NB, 256, 0, stream>>>(aggr2, w10, b10, buf0);
    bn_stats_part<<<NB, 256, 0, stream>>>(buf0, part);
    bn_finalize<<<HID, 256, 0, stream>>>(part, NB, g0v, be0, scsh);
    gemm_mfma<1, 1><<<GG, 256, 0, stream>>>(buf0, scsh, whA, wlA, b20, buf1);

    // ---- hidden layers: h stays in buf1; A split pair in buf2; h1 in buf0 ----
    for (int i = 0; i < 3; ++i) {
        aggregate_kernel<<<NNODES / 16, 256, 0, stream>>>(buf1, rp, srcp, eap,
            ewS + (size_t)i * HID * 7, ebS + (size_t)i * HID, Ahi, Alo);
        gemm1_lds<<<GG, 256, 0, stream>>>(Ahi, Alo,
            whA + (size_t)(1 + i) * 16384, wlA + (size_t)(1 + i) * 16384,
            b1S + (size_t)i * HID, buf0, part);                 // h1 -> buf0 + BN partials
        bn_finalize<<<HID, 256, 0, stream>>>(part, GG,
            gS + (size_t)i * HID, beS + (size_t)i * HID, scsh);
        gemm_mfma<1, 1><<<GG, 256, 0, stream>>>(buf0, scsh,
            whA + (size_t)(4 + i) * 16384, wlA + (size_t)(4 + i) * 16384,
            b2S + (size_t)i * HID, buf1);                       // h -> buf1
    }

    // ---- pooling + reghead ----
    hipMemsetAsync(sums, 0, (size_t)(NGRAPH * HID + NGRAPH) * sizeof(float), stream);
    pool_kernel<<<(NNODES + 127) / 128, 256, 0, stream>>>(buf1, batch, sums, cnt);
    reghead_kernel<<<NGRAPH / 8, 512, 0, stream>>>(sums, cnt, wr, br, we, be_, out);
}

// Round 15
// 669.566 us; speedup vs baseline: 1.1070x; 1.1070x over previous
//
#include <hip/hip_runtime.h>

#define NNODES 100000
#define NEDGES 600000
#define NGRAPH 64
#define HID 128
#define RHD 500
#define NB ((NNODES + 255) / 256)            // 391
#define EB ((NEDGES + 255) / 256)            // 2344
#define GG ((NNODES + 63) / 64)              // 1563 mfma gemm blocks

typedef __attribute__((ext_vector_type(8))) short short8;
typedef __attribute__((ext_vector_type(4))) float f32x4;

__device__ __forceinline__ float leaky1(float x) { return x >= 0.0f ? x : 0.01f * x; }

// fp32 -> bf16 hi + bf16 lo (round-to-nearest-even both)
__device__ __forceinline__ void splitf(float a, unsigned short& h, unsigned short& l)
{
    unsigned u = __float_as_uint(a);
    unsigned r = (u + 0x7FFFu + ((u >> 16) & 1u)) & 0xFFFF0000u;
    h = (unsigned short)(r >> 16);
    float res = a - __uint_as_float(r);
    unsigned u2 = __float_as_uint(res);
    l = (unsigned short)((u2 + 0x7FFFu + ((u2 >> 16) & 1u)) >> 16);
}

// ================= CSR build (deterministic) =================
__global__ __launch_bounds__(256) void hist_kernel(
    const int* __restrict__ ei, int* __restrict__ deg)
{
    int e = blockIdx.x * 256 + threadIdx.x;
    if (e < NEDGES) atomicAdd(&deg[ei[NEDGES + e]], 1);
}

__global__ __launch_bounds__(256) void scan_blk(
    const int* __restrict__ deg, int* __restrict__ incl, int* __restrict__ bsum)
{
    __shared__ int s[256];
    int t = threadIdx.x;
    int n = blockIdx.x * 256 + t;
    int v = (n < NNODES) ? deg[n] : 0;
    int x = v;
    s[t] = x;
    __syncthreads();
    for (int off = 1; off < 256; off <<= 1) {
        int y = (t >= off) ? s[t - off] : 0;
        __syncthreads();
        x += y; s[t] = x;
        __syncthreads();
    }
    if (n < NNODES) incl[n] = x;
    if (t == 255) bsum[blockIdx.x] = x;
}

__global__ __launch_bounds__(512) void scan_bsum(int* __restrict__ bsum, int nblk)
{
    __shared__ int s[512];
    int t = threadIdx.x;
    int v = (t < nblk) ? bsum[t] : 0;
    int x = v;
    s[t] = x;
    __syncthreads();
    for (int off = 1; off < 512; off <<= 1) {
        int y = (t >= off) ? s[t - off] : 0;
        __syncthreads();
        x += y; s[t] = x;
        __syncthreads();
    }
    if (t < nblk) bsum[t] = x - v;   // exclusive
}

__global__ __launch_bounds__(256) void finalize_rp(
    const int* __restrict__ deg, const int* __restrict__ bsum,
    int* __restrict__ rp, int* __restrict__ cursor)
{
    int n = blockIdx.x * 256 + threadIdx.x;
    if (n >= NNODES) return;
    int ig = rp[n] + bsum[blockIdx.x];   // global inclusive
    int st = ig - deg[n];
    rp[n] = st;
    cursor[n] = st;
    if (n == NNODES - 1) rp[NNODES] = ig;
}

__global__ __launch_bounds__(256) void scatter_kernel(
    const int* __restrict__ ei, int* __restrict__ cursor, int* __restrict__ eid)
{
    int e = blockIdx.x * 256 + threadIdx.x;
    if (e >= NEDGES) return;
    int d = ei[NEDGES + e];
    int pos = atomicAdd(&cursor[d], 1);
    eid[pos] = e;
}

__global__ __launch_bounds__(256) void seg_sort(
    const int* __restrict__ rp, int* __restrict__ eid)
{
    int n = blockIdx.x * 256 + threadIdx.x;
    if (n >= NNODES) return;
    int beg = rp[n], end = rp[n + 1];
    for (int i = beg + 1; i < end; ++i) {
        int key = eid[i];
        int j = i - 1;
        while (j >= beg && eid[j] > key) { eid[j + 1] = eid[j]; --j; }
        eid[j + 1] = key;
    }
}

__global__ __launch_bounds__(256) void permute_kernel(
    const int* __restrict__ eid, const int* __restrict__ ei,
    const float* __restrict__ ea, int* __restrict__ srcp, float* __restrict__ eap)
{
    int p = blockIdx.x * 256 + threadIdx.x;
    if (p >= NEDGES) return;
    int id = eid[p];
    srcp[p] = ei[id];
    const float* s = ea + (size_t)id * 7;
    float* d = eap + (size_t)p * 7;
#pragma unroll
    for (int k = 0; k < 7; ++k) d[k] = s[k];
}

// ================= W split: 7 fp32 [128][128] -> bf16 hi/lo, one launch =================
__global__ __launch_bounds__(256) void wsplit_all(
    const float* __restrict__ w20, const float* __restrict__ w1S,
    const float* __restrict__ w2S,
    unsigned short* __restrict__ wh, unsigned short* __restrict__ wl)
{
    int i = blockIdx.x * 256 + threadIdx.x;   // 7*16384 = 114688
    int m = i >> 14;
    int off = i & 16383;
    const float* src;
    if (m == 0) src = w20;
    else if (m <= 3) src = w1S + (size_t)(m - 1) * 16384;
    else src = w2S + (size_t)(m - 4) * 16384;
    unsigned short h, l;
    splitf(src[off], h, l);
    wh[i] = h;
    wl[i] = l;
}

// ================= layer 0 aggregate (d=2) =================
__global__ __launch_bounds__(256) void aggregate0_kernel(
    const float* __restrict__ x, const int* __restrict__ rp,
    const int* __restrict__ srcp, const float* __restrict__ eap,
    const float* __restrict__ ew, const float* __restrict__ eb,
    float* __restrict__ aggr2)
{
    int n = blockIdx.x * 256 + threadIdx.x;
    if (n >= NNODES) return;
    float w0[7], w1[7];
#pragma unroll
    for (int k = 0; k < 7; ++k) { w0[k] = ew[k]; w1[k] = ew[7 + k]; }
    float e0b = eb[0], e1b = eb[1];
    float a0 = x[n * 2 + 0], a1 = x[n * 2 + 1];
    int beg = rp[n], end = rp[n + 1];
    for (int e = beg; e < end; ++e) {
        int s = srcp[e];
        const float* ap = eap + (size_t)e * 7;
        float t0 = e0b, t1 = e1b;
#pragma unroll
        for (int k = 0; k < 7; ++k) {
            float av = ap[k];
            t0 = fmaf(av, w0[k], t0);
            t1 = fmaf(av, w1[k], t1);
        }
        a0 += fmaxf(x[s * 2 + 0] + t0, 0.0f);
        a1 += fmaxf(x[s * 2 + 1] + t1, 0.0f);
    }
    aggr2[n * 2 + 0] = a0;
    aggr2[n * 2 + 1] = a1;
}

// ================= hidden aggregate: wave per 8 nodes, lane owns ch (l, l+64), 4-deep =================
// Writes bf16 hi/lo split pair directly (bitwise-identical to splitting in gemm1).
__global__ __launch_bounds__(256) void aggregate_kernel(
    const float* __restrict__ hin, const int* __restrict__ rp,
    const int* __restrict__ srcp, const float* __restrict__ eap,
    const float* __restrict__ ew, const float* __restrict__ eb,
    unsigned short* __restrict__ Ahi, unsigned short* __restrict__ Alo)
{
    int lane = threadIdx.x & 63;
    int w = threadIdx.x >> 6;
    int nbase = blockIdx.x * 32 + w * 8;
    float ew0[7], ew1[7];
#pragma unroll
    for (int k = 0; k < 7; ++k) {
        ew0[k] = ew[lane * 7 + k];
        ew1[k] = ew[(lane + 64) * 7 + k];
    }
    float eb0v = eb[lane], eb1v = eb[lane + 64];
    for (int n = nbase; n < nbase + 8; ++n) {
        float a0 = hin[(size_t)n * HID + lane];
        float a1 = hin[(size_t)n * HID + 64 + lane];
        int beg = rp[n], end = rp[n + 1];
        int e = beg;
        for (; e + 4 <= end; e += 4) {
            int s0 = srcp[e], s1 = srcp[e + 1], s2 = srcp[e + 2], s3 = srcp[e + 3];
            const float* ap = eap + (size_t)e * 7;
            float x00 = hin[(size_t)s0 * HID + lane];
            float x01 = hin[(size_t)s0 * HID + 64 + lane];
            float x10 = hin[(size_t)s1 * HID + lane];
            float x11 = hin[(size_t)s1 * HID + 64 + lane];
            float x20 = hin[(size_t)s2 * HID + lane];
            float x21 = hin[(size_t)s2 * HID + 64 + lane];
            float x30 = hin[(size_t)s3 * HID + lane];
            float x31 = hin[(size_t)s3 * HID + 64 + lane];
            float t00 = eb0v, t01 = eb1v, t10 = eb0v, t11 = eb1v;
            float t20 = eb0v, t21 = eb1v, t30 = eb0v, t31 = eb1v;
#pragma unroll
            for (int k = 0; k < 7; ++k) {
                float av0 = ap[k], av1 = ap[7 + k], av2 = ap[14 + k], av3 = ap[21 + k];
                t00 = fmaf(av0, ew0[k], t00); t01 = fmaf(av0, ew1[k], t01);
                t10 = fmaf(av1, ew0[k], t10); t11 = fmaf(av1, ew1[k], t11);
                t20 = fmaf(av2, ew0[k], t20); t21 = fmaf(av2, ew1[k], t21);
                t30 = fmaf(av3, ew0[k], t30); t31 = fmaf(av3, ew1[k], t31);
            }
            a0 += fmaxf(x00 + t00, 0.0f);
            a1 += fmaxf(x01 + t01, 0.0f);
            a0 += fmaxf(x10 + t10, 0.0f);
            a1 += fmaxf(x11 + t11, 0.0f);
            a0 += fmaxf(x20 + t20, 0.0f);
            a1 += fmaxf(x21 + t21, 0.0f);
            a0 += fmaxf(x30 + t30, 0.0f);
            a1 += fmaxf(x31 + t31, 0.0f);
        }
        for (; e < end; ++e) {
            int s = srcp[e];
            const float* ap = eap + (size_t)e * 7;
            float t0 = eb0v, t1 = eb1v;
#pragma unroll
            for (int k = 0; k < 7; ++k) {
                float av = ap[k];
                t0 = fmaf(av, ew0[k], t0);
                t1 = fmaf(av, ew1[k], t1);
            }
            float x0 = hin[(size_t)s * HID + lane];
            float x1 = hin[(size_t)s * HID + 64 + lane];
            a0 += fmaxf(x0 + t0, 0.0f);
            a1 += fmaxf(x1 + t1, 0.0f);
        }
        unsigned short h0, l0, h1v, l1v;
        splitf(a0, h0, l0);
        splitf(a1, h1v, l1v);
        size_t rb = (size_t)n * HID;
        Ahi[rb + lane] = h0;
        Ahi[rb + 64 + lane] = h1v;
        Alo[rb + lane] = l0;
        Alo[rb + 64 + lane] = l1v;
    }
}

// ================= layer 0 GEMM1 (in=2 -> 128) =================
__global__ __launch_bounds__(256) void gemm1_l0_kernel(
    const float* __restrict__ aggr2,
    const float* __restrict__ w1, const float* __restrict__ b1,
    float* __restrict__ h1)
{
    int n = blockIdx.x * 256 + threadIdx.x;
    if (n >= NNODES) return;
    float x0 = aggr2[n * 2 + 0];
    float x1 = aggr2[n * 2 + 1];
    float4* out4 = (float4*)(h1 + (size_t)n * HID);
    for (int j = 0; j < HID; j += 4) {
        float4 o;
        o.x = fmaf(x1, w1[(j + 0) * 2 + 1], fmaf(x0, w1[(j + 0) * 2 + 0], b1[j + 0]));
        o.y = fmaf(x1, w1[(j + 1) * 2 + 1], fmaf(x0, w1[(j + 1) * 2 + 0], b1[j + 1]));
        o.z = fmaf(x1, w1[(j + 2) * 2 + 1], fmaf(x0, w1[(j + 2) * 2 + 0], b1[j + 2]));
        o.w = fmaf(x1, w1[(j + 3) * 2 + 1], fmaf(x0, w1[(j + 3) * 2 + 0], b1[j + 3]));
        out4[j >> 2] = o;
    }
}

// ================= BN partial stats (layer 0 only) =================
__global__ __launch_bounds__(256) void bn_stats_part(
    const float* __restrict__ h1, float* __restrict__ part)
{
    __shared__ float ls[HID], lq[HID];
    int c = threadIdx.x & 127;
    int half = threadIdx.x >> 7;
    int base = blockIdx.x * 256;
    int end = base + 256; if (end > NNODES) end = NNODES;
    float s = 0.0f, q = 0.0f;
    for (int r = base + half; r < end; r += 2) {
        float v = h1[(size_t)r * HID + c];
        s += v;
        q = fmaf(v, v, q);
    }
    if (half) { ls[c] = s; lq[c] = q; }
    __syncthreads();
    if (!half) {
        s += ls[c]; q += lq[c];
        part[(size_t)blockIdx.x * 256 + c] = s;
        part[(size_t)blockIdx.x * 256 + 128 + c] = q;
    }
}

// ================= BN finalize -> scale/shift (256 thr/block, HID blocks) =================
__global__ __launch_bounds__(256) void bn_finalize(
    const float* __restrict__ part, int nblk,
    const float* __restrict__ gamma, const float* __restrict__ beta,
    float* __restrict__ scsh)
{
    __shared__ float ls[256], lq[256];
    int c = blockIdx.x;            // 0..127
    int t = threadIdx.x;
    float s = 0.0f, q = 0.0f;
    for (int i = t; i < nblk; i += 256) {
        s += part[(size_t)i * 256 + c];
        q += part[(size_t)i * 256 + 128 + c];
    }
    ls[t] = s; lq[t] = q;
    __syncthreads();
#pragma unroll
    for (int off = 128; off >= 1; off >>= 1) {
        if (t < off) { ls[t] += ls[t + off]; lq[t] += lq[t + off]; }
        __syncthreads();
    }
    if (t == 0) {
        const float invN = 1.0f / (float)NNODES;
        float mu = ls[0] * invN;
        float var = fmaf(-mu, mu, lq[0] * invN);
        float iv = rsqrtf(var + 1e-5f);
        float sc = gamma[c] * iv;
        scsh[c] = sc;
        scsh[HID + c] = beta[c] - mu * sc;
    }
}

// ================= GEMM1 (LDS-staged bf16 pair): h1 = A @ W1^T + b1 + BN partials =================
__global__ __launch_bounds__(256) void gemm1_lds(
    const unsigned short* __restrict__ Ahi, const unsigned short* __restrict__ Alo,
    const unsigned short* __restrict__ wh, const unsigned short* __restrict__ wl,
    const float* __restrict__ b1, float* __restrict__ h1,
    float* __restrict__ part)
{
    __shared__ __align__(16) short lds[16384];   // 32KB: hi [0,16KB), lo [16KB,32KB)
    const int t = threadIdx.x;
    const int mb = blockIdx.x * 64;

#pragma unroll
    for (int u = 0; u < 4; ++u) {
        int idx = u * 256 + t;
        int row = idx >> 4, sl = idx & 15;
        int gr = mb + row;
        short8 hv, lv;
#pragma unroll
        for (int e = 0; e < 8; ++e) { hv[e] = 0; lv[e] = 0; }
        if (gr < NNODES) {
            hv = *(const short8*)(Ahi + (size_t)gr * HID + sl * 8);
            lv = *(const short8*)(Alo + (size_t)gr * HID + sl * 8);
        }
        int byt = row * 256 + ((sl ^ (row & 7)) << 4);
        *(short8*)((char*)lds + byt) = hv;
        *(short8*)((char*)lds + 16384 + byt) = lv;
    }
    __syncthreads();

    const int lane = t & 63;
    const int wv = t >> 6;
    const int cl = lane & 15, g = lane >> 4, x = lane & 7;
    const int colbase = wv * 32;

    int aoff[4];
#pragma unroll
    for (int ks = 0; ks < 4; ++ks)
        aoff[ks] = cl * 256 + (((ks * 4 + g) ^ x) << 4);

    const unsigned short* wb_h0 = wh + (size_t)(colbase + cl) * HID + g * 8;
    const unsigned short* wb_h1 = wb_h0 + 16 * HID;
    const unsigned short* wb_l0 = wl + (size_t)(colbase + cl) * HID + g * 8;
    const unsigned short* wb_l1 = wb_l0 + 16 * HID;

    f32x4 acc[4][2];
#pragma unroll
    for (int rt = 0; rt < 4; ++rt) {
        acc[rt][0] = (f32x4){0.f, 0.f, 0.f, 0.f};
        acc[rt][1] = (f32x4){0.f, 0.f, 0.f, 0.f};
    }

#pragma unroll
    for (int ks = 0; ks < 4; ++ks) {
        short8 bh0 = *(const short8*)(wb_h0 + ks * 32);
        short8 bh1 = *(const short8*)(wb_h1 + ks * 32);
        short8 bl0 = *(const short8*)(wb_l0 + ks * 32);
        short8 bl1 = *(const short8*)(wb_l1 + ks * 32);
#pragma unroll
        for (int rt = 0; rt < 4; ++rt) {
            short8 ah = *(const short8*)((const char*)lds + (rt * 4096) + aoff[ks]);
            short8 al = *(const short8*)((const char*)lds + (16384 + rt * 4096) + aoff[ks]);
            acc[rt][0] = __builtin_amdgcn_mfma_f32_16x16x32_bf16(ah, bh0, acc[rt][0], 0, 0, 0);
            acc[rt][1] = __builtin_amdgcn_mfma_f32_16x16x32_bf16(ah, bh1, acc[rt][1], 0, 0, 0);
            acc[rt][0] = __builtin_amdgcn_mfma_f32_16x16x32_bf16(al, bh0, acc[rt][0], 0, 0, 0);
            acc[rt][1] = __builtin_amdgcn_mfma_f32_16x16x32_bf16(al, bh1, acc[rt][1], 0, 0, 0);
            acc[rt][0] = __builtin_amdgcn_mfma_f32_16x16x32_bf16(ah, bl0, acc[rt][0], 0, 0, 0);
            acc[rt][1] = __builtin_amdgcn_mfma_f32_16x16x32_bf16(ah, bl1, acc[rt][1], 0, 0, 0);
        }
    }

    float bj0 = b1[colbase + cl];
    float bj1 = b1[colbase + 16 + cl];
    float s0 = 0.f, q0 = 0.f, s1 = 0.f, q1 = 0.f;
#pragma unroll
    for (int rt = 0; rt < 4; ++rt) {
        int rbase = mb + rt * 16 + g * 4;
#pragma unroll
        for (int r = 0; r < 4; ++r) {
            int grow = rbase + r;
            if (grow < NNODES) {
                float o0 = acc[rt][0][r] + bj0;
                float o1 = acc[rt][1][r] + bj1;
                h1[(size_t)grow * HID + colbase + cl] = o0;
                h1[(size_t)grow * HID + colbase + 16 + cl] = o1;
                s0 += o0; q0 = fmaf(o0, o0, q0);
                s1 += o1; q1 = fmaf(o1, o1, q1);
            }
        }
    }
    __syncthreads();                 // LDS frag reads done; reuse as scratch
    float* red = (float*)lds;        // 1024 floats
    red[(colbase + cl) * 4 + g] = s0;
    red[(colbase + 16 + cl) * 4 + g] = s1;
    red[512 + (colbase + cl) * 4 + g] = q0;
    red[512 + (colbase + 16 + cl) * 4 + g] = q1;
    __syncthreads();
    {
        int stat = t >> 7, col = t & 127;
        const float* bp = red + stat * 512 + col * 4;
        part[(size_t)blockIdx.x * 256 + stat * 128 + col] = bp[0] + bp[1] + bp[2] + bp[3];
    }
}

// ================= MFMA GEMM2: Hout = leaky(leaky( leaky(BN(Ain)) @ W^T + b )) =================
template<int PRE, int POST>
__global__ __launch_bounds__(256) void gemm_mfma(
    const float* __restrict__ Ain, const float* __restrict__ scsh,
    const unsigned short* __restrict__ wh, const unsigned short* __restrict__ wl,
    const float* __restrict__ bias, float* __restrict__ Hout)
{
    __shared__ __align__(16) short lds[16384];   // 32KB
    const int t = threadIdx.x;
    const int mb = blockIdx.x * 64;

    const float4* sc4 = (const float4*)scsh;
    const float4* sh4 = (const float4*)(scsh + HID);

#pragma unroll
    for (int u = 0; u < 4; ++u) {
        int idx = u * 256 + t;
        int row = idx >> 4, sl = idx & 15;
        float4 v0 = make_float4(0.f, 0.f, 0.f, 0.f);
        float4 v1 = make_float4(0.f, 0.f, 0.f, 0.f);
        int gr = mb + row;
        if (gr < NNODES) {
            const float4* p = (const float4*)(Ain + (size_t)gr * HID + sl * 8);
            v0 = p[0]; v1 = p[1];
            if (PRE) {
                float4 c0 = sc4[sl * 2], c1 = sc4[sl * 2 + 1];
                float4 s0 = sh4[sl * 2], s1 = sh4[sl * 2 + 1];
                v0.x = leaky1(fmaf(v0.x, c0.x, s0.x));
                v0.y = leaky1(fmaf(v0.y, c0.y, s0.y));
                v0.z = leaky1(fmaf(v0.z, c0.z, s0.z));
                v0.w = leaky1(fmaf(v0.w, c0.w, s0.w));
                v1.x = leaky1(fmaf(v1.x, c1.x, s1.x));
                v1.y = leaky1(fmaf(v1.y, c1.y, s1.y));
                v1.z = leaky1(fmaf(v1.z, c1.z, s1.z));
                v1.w = leaky1(fmaf(v1.w, c1.w, s1.w));
            }
        }
        unsigned short h[8], l[8];
        splitf(v0.x, h[0], l[0]); splitf(v0.y, h[1], l[1]);
        splitf(v0.z, h[2], l[2]); splitf(v0.w, h[3], l[3]);
        splitf(v1.x, h[4], l[4]); splitf(v1.y, h[5], l[5]);
        splitf(v1.z, h[6], l[6]); splitf(v1.w, h[7], l[7]);
        short8 hv, lv;
#pragma unroll
        for (int e = 0; e < 8; ++e) { hv[e] = (short)h[e]; lv[e] = (short)l[e]; }
        int byt = row * 256 + ((sl ^ (row & 7)) << 4);
        *(short8*)((char*)lds + byt) = hv;
        *(short8*)((char*)lds + 16384 + byt) = lv;
    }
    __syncthreads();

    const int lane = t & 63;
    const int wv = t >> 6;
    const int cl = lane & 15, g = lane >> 4, x = lane & 7;
    const int colbase = wv * 32;

    int aoff[4];
#pragma unroll
    for (int ks = 0; ks < 4; ++ks)
        aoff[ks] = cl * 256 + (((ks * 4 + g) ^ x) << 4);

    const unsigned short* wb_h0 = wh + (size_t)(colbase + cl) * HID + g * 8;
    const unsigned short* wb_h1 = wb_h0 + 16 * HID;
    const unsigned short* wb_l0 = wl + (size_t)(colbase + cl) * HID + g * 8;
    const unsigned short* wb_l1 = wb_l0 + 16 * HID;

    f32x4 acc[4][2];
#pragma unroll
    for (int rt = 0; rt < 4; ++rt) {
        acc[rt][0] = (f32x4){0.f, 0.f, 0.f, 0.f};
        acc[rt][1] = (f32x4){0.f, 0.f, 0.f, 0.f};
    }

#pragma unroll
    for (int ks = 0; ks < 4; ++ks) {
        short8 bh0 = *(const short8*)(wb_h0 + ks * 32);
        short8 bh1 = *(const short8*)(wb_h1 + ks * 32);
        short8 bl0 = *(const short8*)(wb_l0 + ks * 32);
        short8 bl1 = *(const short8*)(wb_l1 + ks * 32);
#pragma unroll
        for (int rt = 0; rt < 4; ++rt) {
            short8 ah = *(const short8*)((const char*)lds + (rt * 4096) + aoff[ks]);
            short8 al = *(const short8*)((const char*)lds + (16384 + rt * 4096) + aoff[ks]);
            acc[rt][0] = __builtin_amdgcn_mfma_f32_16x16x32_bf16(ah, bh0, acc[rt][0], 0, 0, 0);
            acc[rt][1] = __builtin_amdgcn_mfma_f32_16x16x32_bf16(ah, bh1, acc[rt][1], 0, 0, 0);
            acc[rt][0] = __builtin_amdgcn_mfma_f32_16x16x32_bf16(al, bh0, acc[rt][0], 0, 0, 0);
            acc[rt][1] = __builtin_amdgcn_mfma_f32_16x16x32_bf16(al, bh1, acc[rt][1], 0, 0, 0);
            acc[rt][0] = __builtin_amdgcn_mfma_f32_16x16x32_bf16(ah, bl0, acc[rt][0], 0, 0, 0);
            acc[rt][1] = __builtin_amdgcn_mfma_f32_16x16x32_bf16(ah, bl1, acc[rt][1], 0, 0, 0);
        }
    }

    float bj0 = bias[colbase + cl];
    float bj1 = bias[colbase + 16 + cl];
#pragma unroll
    for (int rt = 0; rt < 4; ++rt) {
        int rbase = mb + rt * 16 + g * 4;
#pragma unroll
        for (int r = 0; r < 4; ++r) {
            int grow = rbase + r;
            if (grow < NNODES) {
                float o0 = acc[rt][0][r] + bj0;
                float o1 = acc[rt][1][r] + bj1;
                if (POST) { o0 = leaky1(leaky1(o0)); o1 = leaky1(leaky1(o1)); }
                Hout[(size_t)grow * HID + colbase + cl] = o0;
                Hout[(size_t)grow * HID + colbase + 16 + cl] = o1;
            }
        }
    }
}

// ================= global mean pool (batch sorted) =================
__global__ __launch_bounds__(256) void pool_kernel(
    const float* __restrict__ h, const int* __restrict__ batch,
    float* __restrict__ sums, float* __restrict__ cnt)
{
    int c = threadIdx.x & 127;
    int half = threadIdx.x >> 7;
    int base = blockIdx.x * 128 + half * 64;
    if (base >= NNODES) return;
    int end = base + 64; if (end > NNODES) end = NNODES;
    int g = batch[base];
    float acc = 0.0f, k = 0.0f;
    for (int n = base; n < end; ++n) {
        int gn = batch[n];
        if (gn != g) {
            atomicAdd(&sums[g * HID + c], acc);
            if (c == 0) atomicAdd(&cnt[g], k);
            acc = 0.0f; k = 0.0f; g = gn;
        }
        acc += h[(size_t)n * HID + c];
        k += 1.0f;
    }
    atomicAdd(&sums[g * HID + c], acc);
    if (c == 0) atomicAdd(&cnt[g], k);
}

// ================= reghead =================
__global__ __launch_bounds__(512) void reghead_kernel(
    const float* __restrict__ sums, const float* __restrict__ cnt,
    const float* __restrict__ wr, const float* __restrict__ br,
    const float* __restrict__ we, const float* __restrict__ be,
    float* __restrict__ out)
{
    __shared__ float pool[8 * HID];
    __shared__ float red[8][8];
    int g0 = blockIdx.x * 8;
    for (int i = threadIdx.x; i < 8 * HID; i += 512) {
        int g = g0 + (i >> 7);
        float c = cnt[g]; c = fmaxf(c, 1.0f);
        pool[i] = sums[g * HID + (i & 127)] / c;
    }
    __syncthreads();
    int j = threadIdx.x;
    float p[8];
#pragma unroll
    for (int g = 0; g < 8; ++g) p[g] = 0.0f;
    if (j < RHD) {
        float accs[8];
        float bjv = br[j];
#pragma unroll
        for (int g = 0; g < 8; ++g) accs[g] = bjv;
        const float4* wr4 = (const float4*)(wr + (size_t)j * HID);
        const float4* pool4 = (const float4*)pool;
        for (int k = 0; k < 32; ++k) {
            float4 w = wr4[k];
#pragma unroll
            for (int g = 0; g < 8; ++g) {
                float4 pv = pool4[g * 32 + k];
                accs[g] = fmaf(w.x, pv.x, accs[g]);
                accs[g] = fmaf(w.y, pv.y, accs[g]);
                accs[g] = fmaf(w.z, pv.z, accs[g]);
                accs[g] = fmaf(w.w, pv.w, accs[g]);
            }
        }
        float wej = we[j];
#pragma unroll
        for (int g = 0; g < 8; ++g) p[g] = leaky1(accs[g]) * wej;
    }
    int lane = threadIdx.x & 63, wid = threadIdx.x >> 6;
#pragma unroll
    for (int g = 0; g < 8; ++g) {
        float v = p[g];
        v += __shfl_down(v, 32); v += __shfl_down(v, 16); v += __shfl_down(v, 8);
        v += __shfl_down(v, 4);  v += __shfl_down(v, 2);  v += __shfl_down(v, 1);
        if (lane == 0) red[g][wid] = v;
    }
    __syncthreads();
    if (threadIdx.x < 8) {
        float sv = be[0];
#pragma unroll
        for (int w = 0; w < 8; ++w) sv += red[threadIdx.x][w];
        out[g0 + threadIdx.x] = sv;
    }
}

extern "C" void kernel_launch(void* const* d_in, const int* in_sizes, int n_in,
                              void* d_out, int out_size, void* d_ws, size_t ws_size,
                              hipStream_t stream)
{
    const float* x     = (const float*)d_in[0];
    const int*   ei    = (const int*)d_in[1];
    const int*   batch = (const int*)d_in[2];
    const float* ea    = (const float*)d_in[3];
    const float* ew0   = (const float*)d_in[4];
    const float* eb0   = (const float*)d_in[5];
    const float* w10   = (const float*)d_in[6];
    const float* b10   = (const float*)d_in[7];
    const float* g0v   = (const float*)d_in[8];
    const float* be0   = (const float*)d_in[9];
    const float* w20   = (const float*)d_in[10];
    const float* b20   = (const float*)d_in[11];
    const float* ewS   = (const float*)d_in[12];
    const float* ebS   = (const float*)d_in[13];
    const float* w1S   = (const float*)d_in[14];
    const float* b1S   = (const float*)d_in[15];
    const float* gS    = (const float*)d_in[16];
    const float* beS   = (const float*)d_in[17];
    const float* w2S   = (const float*)d_in[18];
    const float* b2S   = (const float*)d_in[19];
    const float* wr    = (const float*)d_in[20];
    const float* br    = (const float*)d_in[21];
    const float* we    = (const float*)d_in[22];
    const float* be_   = (const float*)d_in[23];

    float* ws    = (float*)d_ws;
    float* buf0  = ws;                                   // N*128 (h1)
    float* buf1  = buf0 + (size_t)NNODES * HID;          // N*128 (h)
    float* buf2  = buf1 + (size_t)NNODES * HID;          // N*128 (Ahi/Alo bf16 pair)
    unsigned short* Ahi = (unsigned short*)buf2;         // N*128 bf16
    unsigned short* Alo = Ahi + (size_t)NNODES * HID;    // N*128 bf16
    float* part  = buf2 + (size_t)NNODES * HID;          // GG*256
    float* scsh  = part + (size_t)GG * 256;              // 256
    float* sums  = scsh + 256;                           // 64*128
    float* cnt   = sums + NGRAPH * HID;                  // 64
    float* aggr2 = cnt + NGRAPH;                         // N*2
    float* eap   = aggr2 + (size_t)NNODES * 2;           // E*7
    int*   deg    = (int*)(eap + (size_t)NEDGES * 7);    // N
    int*   cursor = deg + NNODES;                        // N
    int*   bsum   = cursor + NNODES;                     // 512
    int*   rp     = bsum + 512;                          // N+1
    int*   eid    = rp + NNODES + 1;                     // E
    int*   srcp   = eid + NEDGES;                        // E
    unsigned short* whA = (unsigned short*)(srcp + NEDGES);  // 7*16384
    unsigned short* wlA = whA + 7 * 16384;                   // 7*16384
    float* out   = (float*)d_out;

    // ---- CSR build (deterministic; once per launch) ----
    hipMemsetAsync(deg, 0, (size_t)NNODES * sizeof(int), stream);
    hist_kernel<<<EB, 256, 0, stream>>>(ei, deg);
    scan_blk<<<NB, 256, 0, stream>>>(deg, rp, bsum);
    scan_bsum<<<1, 512, 0, stream>>>(bsum, NB);
    finalize_rp<<<NB, 256, 0, stream>>>(deg, bsum, rp, cursor);
    scatter_kernel<<<EB, 256, 0, stream>>>(ei, cursor, eid);
    seg_sort<<<NB, 256, 0, stream>>>(rp, eid);
    permute_kernel<<<EB, 256, 0, stream>>>(eid, ei, ea, srcp, eap);

    // ---- weight split: one launch ----
    wsplit_all<<<448, 256, 0, stream>>>(w20, w1S, w2S, whA, wlA);

    // ---- layer 0: h1 -> buf0, h -> buf1 ----
    aggregate0_kernel<<<NB, 256, 0, stream>>>(x, rp, srcp, eap, ew0, eb0, aggr2);
    gemm1_l0_kernel<<<NB, 256, 0, stream>>>(aggr2, w10, b10, buf0);
    bn_stats_part<<<NB, 256, 0, stream>>>(buf0, part);
    bn_finalize<<<HID, 256, 0, stream>>>(part, NB, g0v, be0, scsh);
    gemm_mfma<1, 1><<<GG, 256, 0, stream>>>(buf0, scsh, whA, wlA, b20, buf1);

    // ---- hidden layers: h stays in buf1; A split pair in buf2; h1 in buf0 ----
    for (int i = 0; i < 3; ++i) {
        aggregate_kernel<<<NNODES / 32, 256, 0, stream>>>(buf1, rp, srcp, eap,
            ewS + (size_t)i * HID * 7, ebS + (size_t)i * HID, Ahi, Alo);
        gemm1_lds<<<GG, 256, 0, stream>>>(Ahi, Alo,
            whA + (size_t)(1 + i) * 16384, wlA + (size_t)(1 + i) * 16384,
            b1S + (size_t)i * HID, buf0, part);                 // h1 -> buf0 + BN partials
        bn_finalize<<<HID, 256, 0, stream>>>(part, GG,
            gS + (size_t)i * HID, beS + (size_t)i * HID, scsh);
        gemm_mfma<1, 1><<<GG, 256, 0, stream>>>(buf0, scsh,
            whA + (size_t)(4 + i) * 16384, wlA + (size_t)(4 + i) * 16384,
            b2S + (size_t)i * HID, buf1);                       // h -> buf1
    }

    // ---- pooling + reghead ----
    hipMemsetAsync(sums, 0, (size_t)(NGRAPH * HID + NGRAPH) * sizeof(float), stream);
    pool_kernel<<<(NNODES + 127) / 128, 256, 0, stream>>>(buf1, batch, sums, cnt);
    reghead_kernel<<<NGRAPH / 8, 512, 0, stream>>>(sums, cnt, wr, br, we, be_, out);
}

// Round 16
// 666.399 us; speedup vs baseline: 1.1122x; 1.0048x over previous
//
#include <hip/hip_runtime.h>

#define NNODES 100000
#define NEDGES 600000
#define NGRAPH 64
#define HID 128
#define RHD 500
#define NB ((NNODES + 255) / 256)            // 391
#define EB ((NEDGES + 255) / 256)            // 2344
#define GG ((NNODES + 63) / 64)              // 1563 mfma gemm blocks

typedef __attribute__((ext_vector_type(8))) short short8;
typedef __attribute__((ext_vector_type(4))) float f32x4;

__device__ __forceinline__ float leaky1(float x) { return x >= 0.0f ? x : 0.01f * x; }

// fp32 -> bf16 hi + bf16 lo (round-to-nearest-even both)
__device__ __forceinline__ void splitf(float a, unsigned short& h, unsigned short& l)
{
    unsigned u = __float_as_uint(a);
    unsigned r = (u + 0x7FFFu + ((u >> 16) & 1u)) & 0xFFFF0000u;
    h = (unsigned short)(r >> 16);
    float res = a - __uint_as_float(r);
    unsigned u2 = __float_as_uint(res);
    l = (unsigned short)((u2 + 0x7FFFu + ((u2 >> 16) & 1u)) >> 16);
}

// ================= CSR build (deterministic) =================
__global__ __launch_bounds__(256) void hist_kernel(
    const int* __restrict__ ei, int* __restrict__ deg)
{
    int e = blockIdx.x * 256 + threadIdx.x;
    if (e < NEDGES) atomicAdd(&deg[ei[NEDGES + e]], 1);
}

__global__ __launch_bounds__(256) void scan_blk(
    const int* __restrict__ deg, int* __restrict__ incl, int* __restrict__ bsum)
{
    __shared__ int s[256];
    int t = threadIdx.x;
    int n = blockIdx.x * 256 + t;
    int v = (n < NNODES) ? deg[n] : 0;
    int x = v;
    s[t] = x;
    __syncthreads();
    for (int off = 1; off < 256; off <<= 1) {
        int y = (t >= off) ? s[t - off] : 0;
        __syncthreads();
        x += y; s[t] = x;
        __syncthreads();
    }
    if (n < NNODES) incl[n] = x;
    if (t == 255) bsum[blockIdx.x] = x;
}

__global__ __launch_bounds__(512) void scan_bsum(int* __restrict__ bsum, int nblk)
{
    __shared__ int s[512];
    int t = threadIdx.x;
    int v = (t < nblk) ? bsum[t] : 0;
    int x = v;
    s[t] = x;
    __syncthreads();
    for (int off = 1; off < 512; off <<= 1) {
        int y = (t >= off) ? s[t - off] : 0;
        __syncthreads();
        x += y; s[t] = x;
        __syncthreads();
    }
    if (t < nblk) bsum[t] = x - v;   // exclusive
}

__global__ __launch_bounds__(256) void finalize_rp(
    const int* __restrict__ deg, const int* __restrict__ bsum,
    int* __restrict__ rp, int* __restrict__ cursor)
{
    int n = blockIdx.x * 256 + threadIdx.x;
    if (n >= NNODES) return;
    int ig = rp[n] + bsum[blockIdx.x];   // global inclusive
    int st = ig - deg[n];
    rp[n] = st;
    cursor[n] = st;
    if (n == NNODES - 1) rp[NNODES] = ig;
}

__global__ __launch_bounds__(256) void scatter_kernel(
    const int* __restrict__ ei, int* __restrict__ cursor, int* __restrict__ eid)
{
    int e = blockIdx.x * 256 + threadIdx.x;
    if (e >= NEDGES) return;
    int d = ei[NEDGES + e];
    int pos = atomicAdd(&cursor[d], 1);
    eid[pos] = e;
}

__global__ __launch_bounds__(256) void seg_sort(
    const int* __restrict__ rp, int* __restrict__ eid)
{
    int n = blockIdx.x * 256 + threadIdx.x;
    if (n >= NNODES) return;
    int beg = rp[n], end = rp[n + 1];
    for (int i = beg + 1; i < end; ++i) {
        int key = eid[i];
        int j = i - 1;
        while (j >= beg && eid[j] > key) { eid[j + 1] = eid[j]; --j; }
        eid[j + 1] = key;
    }
}

__global__ __launch_bounds__(256) void permute_kernel(
    const int* __restrict__ eid, const int* __restrict__ ei,
    const float* __restrict__ ea, int* __restrict__ srcp, float* __restrict__ eap)
{
    int p = blockIdx.x * 256 + threadIdx.x;
    if (p >= NEDGES) return;
    int id = eid[p];
    srcp[p] = ei[id];
    const float* s = ea + (size_t)id * 7;
    float* d = eap + (size_t)p * 7;
#pragma unroll
    for (int k = 0; k < 7; ++k) d[k] = s[k];
}

// ================= W split: 7 fp32 [128][128] -> bf16 hi/lo, one launch =================
__global__ __launch_bounds__(256) void wsplit_all(
    const float* __restrict__ w20, const float* __restrict__ w1S,
    const float* __restrict__ w2S,
    unsigned short* __restrict__ wh, unsigned short* __restrict__ wl)
{
    int i = blockIdx.x * 256 + threadIdx.x;   // 7*16384 = 114688
    int m = i >> 14;
    int off = i & 16383;
    const float* src;
    if (m == 0) src = w20;
    else if (m <= 3) src = w1S + (size_t)(m - 1) * 16384;
    else src = w2S + (size_t)(m - 4) * 16384;
    unsigned short h, l;
    splitf(src[off], h, l);
    wh[i] = h;
    wl[i] = l;
}

// ================= layer 0 aggregate (d=2) =================
__global__ __launch_bounds__(256) void aggregate0_kernel(
    const float* __restrict__ x, const int* __restrict__ rp,
    const int* __restrict__ srcp, const float* __restrict__ eap,
    const float* __restrict__ ew, const float* __restrict__ eb,
    float* __restrict__ aggr2)
{
    int n = blockIdx.x * 256 + threadIdx.x;
    if (n >= NNODES) return;
    float w0[7], w1[7];
#pragma unroll
    for (int k = 0; k < 7; ++k) { w0[k] = ew[k]; w1[k] = ew[7 + k]; }
    float e0b = eb[0], e1b = eb[1];
    float a0 = x[n * 2 + 0], a1 = x[n * 2 + 1];
    int beg = rp[n], end = rp[n + 1];
    for (int e = beg; e < end; ++e) {
        int s = srcp[e];
        const float* ap = eap + (size_t)e * 7;
        float t0 = e0b, t1 = e1b;
#pragma unroll
        for (int k = 0; k < 7; ++k) {
            float av = ap[k];
            t0 = fmaf(av, w0[k], t0);
            t1 = fmaf(av, w1[k], t1);
        }
        a0 += fmaxf(x[s * 2 + 0] + t0, 0.0f);
        a1 += fmaxf(x[s * 2 + 1] + t1, 0.0f);
    }
    aggr2[n * 2 + 0] = a0;
    aggr2[n * 2 + 1] = a1;
}

// ================= hidden aggregate: streaming segmented, wave per 8 nodes, lane owns (l, l+64) =================
// Edge pipeline runs 4-deep across the merged 8-node CSR span (no drain at node
// boundaries); wave-uniform emit preserves per-node edge order -> bitwise identical.
__global__ __launch_bounds__(256) void aggregate_kernel(
    const float* __restrict__ hin, const int* __restrict__ rp,
    const int* __restrict__ srcp, const float* __restrict__ eap,
    const float* __restrict__ ew, const float* __restrict__ eb,
    unsigned short* __restrict__ Ahi, unsigned short* __restrict__ Alo)
{
    const int lane = threadIdx.x & 63;
    const int w = threadIdx.x >> 6;
    const int nbase = blockIdx.x * 32 + w * 8;
    const int nend = nbase + 8;

    float ew0[7], ew1[7];
#pragma unroll
    for (int k = 0; k < 7; ++k) {
        ew0[k] = ew[lane * 7 + k];
        ew1[k] = ew[(lane + 64) * 7 + k];
    }
    const float eb0v = eb[lane], eb1v = eb[lane + 64];

    int n = nbase;
    int e = rp[nbase];
    const int eend = rp[nend];
    int next = rp[n + 1];
    float a0 = hin[(size_t)n * HID + lane];
    float a1 = hin[(size_t)n * HID + 64 + lane];

#define EMIT_ADVANCE() { \
        unsigned short hh0, ll0, hh1, ll1; \
        splitf(a0, hh0, ll0); splitf(a1, hh1, ll1); \
        size_t rb = (size_t)n * HID; \
        Ahi[rb + lane] = hh0; Ahi[rb + 64 + lane] = hh1; \
        Alo[rb + lane] = ll0; Alo[rb + 64 + lane] = ll1; \
        ++n; \
        a0 = hin[(size_t)n * HID + lane]; \
        a1 = hin[(size_t)n * HID + 64 + lane]; \
        next = rp[n + 1]; }

    while (e + 4 <= eend) {
        int s0 = srcp[e], s1 = srcp[e + 1], s2 = srcp[e + 2], s3 = srcp[e + 3];
        const float* ap = eap + (size_t)e * 7;
        float x00 = hin[(size_t)s0 * HID + lane];
        float x01 = hin[(size_t)s0 * HID + 64 + lane];
        float x10 = hin[(size_t)s1 * HID + lane];
        float x11 = hin[(size_t)s1 * HID + 64 + lane];
        float x20 = hin[(size_t)s2 * HID + lane];
        float x21 = hin[(size_t)s2 * HID + 64 + lane];
        float x30 = hin[(size_t)s3 * HID + lane];
        float x31 = hin[(size_t)s3 * HID + 64 + lane];
        float t00 = eb0v, t01 = eb1v, t10 = eb0v, t11 = eb1v;
        float t20 = eb0v, t21 = eb1v, t30 = eb0v, t31 = eb1v;
#pragma unroll
        for (int k = 0; k < 7; ++k) {
            float av0 = ap[k], av1 = ap[7 + k], av2 = ap[14 + k], av3 = ap[21 + k];
            t00 = fmaf(av0, ew0[k], t00); t01 = fmaf(av0, ew1[k], t01);
            t10 = fmaf(av1, ew0[k], t10); t11 = fmaf(av1, ew1[k], t11);
            t20 = fmaf(av2, ew0[k], t20); t21 = fmaf(av2, ew1[k], t21);
            t30 = fmaf(av3, ew0[k], t30); t31 = fmaf(av3, ew1[k], t31);
        }
        float m00 = fmaxf(x00 + t00, 0.0f), m01 = fmaxf(x01 + t01, 0.0f);
        float m10 = fmaxf(x10 + t10, 0.0f), m11 = fmaxf(x11 + t11, 0.0f);
        float m20 = fmaxf(x20 + t20, 0.0f), m21 = fmaxf(x21 + t21, 0.0f);
        float m30 = fmaxf(x30 + t30, 0.0f), m31 = fmaxf(x31 + t31, 0.0f);
        while (e >= next)     EMIT_ADVANCE();
        a0 += m00; a1 += m01;
        while (e + 1 >= next) EMIT_ADVANCE();
        a0 += m10; a1 += m11;
        while (e + 2 >= next) EMIT_ADVANCE();
        a0 += m20; a1 += m21;
        while (e + 3 >= next) EMIT_ADVANCE();
        a0 += m30; a1 += m31;
        e += 4;
    }
    for (; e < eend; ++e) {
        int s = srcp[e];
        const float* ap = eap + (size_t)e * 7;
        float xv0 = hin[(size_t)s * HID + lane];
        float xv1 = hin[(size_t)s * HID + 64 + lane];
        float t0 = eb0v, t1 = eb1v;
#pragma unroll
        for (int k = 0; k < 7; ++k) {
            float av = ap[k];
            t0 = fmaf(av, ew0[k], t0);
            t1 = fmaf(av, ew1[k], t1);
        }
        while (e >= next) EMIT_ADVANCE();
        a0 += fmaxf(xv0 + t0, 0.0f);
        a1 += fmaxf(xv1 + t1, 0.0f);
    }
#undef EMIT_ADVANCE
    // flush remaining nodes (handles trailing zero-degree nodes)
    while (n < nend) {
        unsigned short hh0, ll0, hh1, ll1;
        splitf(a0, hh0, ll0); splitf(a1, hh1, ll1);
        size_t rb = (size_t)n * HID;
        Ahi[rb + lane] = hh0; Ahi[rb + 64 + lane] = hh1;
        Alo[rb + lane] = ll0; Alo[rb + 64 + lane] = ll1;
        ++n;
        if (n < nend) {
            a0 = hin[(size_t)n * HID + lane];
            a1 = hin[(size_t)n * HID + 64 + lane];
            next = rp[n + 1];
        }
    }
}

// ================= layer 0 GEMM1 (in=2 -> 128) =================
__global__ __launch_bounds__(256) void gemm1_l0_kernel(
    const float* __restrict__ aggr2,
    const float* __restrict__ w1, const float* __restrict__ b1,
    float* __restrict__ h1)
{
    int n = blockIdx.x * 256 + threadIdx.x;
    if (n >= NNODES) return;
    float x0 = aggr2[n * 2 + 0];
    float x1 = aggr2[n * 2 + 1];
    float4* out4 = (float4*)(h1 + (size_t)n * HID);
    for (int j = 0; j < HID; j += 4) {
        float4 o;
        o.x = fmaf(x1, w1[(j + 0) * 2 + 1], fmaf(x0, w1[(j + 0) * 2 + 0], b1[j + 0]));
        o.y = fmaf(x1, w1[(j + 1) * 2 + 1], fmaf(x0, w1[(j + 1) * 2 + 0], b1[j + 1]));
        o.z = fmaf(x1, w1[(j + 2) * 2 + 1], fmaf(x0, w1[(j + 2) * 2 + 0], b1[j + 2]));
        o.w = fmaf(x1, w1[(j + 3) * 2 + 1], fmaf(x0, w1[(j + 3) * 2 + 0], b1[j + 3]));
        out4[j >> 2] = o;
    }
}

// ================= BN partial stats (layer 0 only) =================
__global__ __launch_bounds__(256) void bn_stats_part(
    const float* __restrict__ h1, float* __restrict__ part)
{
    __shared__ float ls[HID], lq[HID];
    int c = threadIdx.x & 127;
    int half = threadIdx.x >> 7;
    int base = blockIdx.x * 256;
    int end = base + 256; if (end > NNODES) end = NNODES;
    float s = 0.0f, q = 0.0f;
    for (int r = base + half; r < end; r += 2) {
        float v = h1[(size_t)r * HID + c];
        s += v;
        q = fmaf(v, v, q);
    }
    if (half) { ls[c] = s; lq[c] = q; }
    __syncthreads();
    if (!half) {
        s += ls[c]; q += lq[c];
        part[(size_t)blockIdx.x * 256 + c] = s;
        part[(size_t)blockIdx.x * 256 + 128 + c] = q;
    }
}

// ================= BN finalize -> scale/shift (256 thr/block, HID blocks) =================
__global__ __launch_bounds__(256) void bn_finalize(
    const float* __restrict__ part, int nblk,
    const float* __restrict__ gamma, const float* __restrict__ beta,
    float* __restrict__ scsh)
{
    __shared__ float ls[256], lq[256];
    int c = blockIdx.x;            // 0..127
    int t = threadIdx.x;
    float s = 0.0f, q = 0.0f;
    for (int i = t; i < nblk; i += 256) {
        s += part[(size_t)i * 256 + c];
        q += part[(size_t)i * 256 + 128 + c];
    }
    ls[t] = s; lq[t] = q;
    __syncthreads();
#pragma unroll
    for (int off = 128; off >= 1; off >>= 1) {
        if (t < off) { ls[t] += ls[t + off]; lq[t] += lq[t + off]; }
        __syncthreads();
    }
    if (t == 0) {
        const float invN = 1.0f / (float)NNODES;
        float mu = ls[0] * invN;
        float var = fmaf(-mu, mu, lq[0] * invN);
        float iv = rsqrtf(var + 1e-5f);
        float sc = gamma[c] * iv;
        scsh[c] = sc;
        scsh[HID + c] = beta[c] - mu * sc;
    }
}

// ================= GEMM1 (LDS-staged bf16 pair): h1 = A @ W1^T + b1 + BN partials =================
__global__ __launch_bounds__(256) void gemm1_lds(
    const unsigned short* __restrict__ Ahi, const unsigned short* __restrict__ Alo,
    const unsigned short* __restrict__ wh, const unsigned short* __restrict__ wl,
    const float* __restrict__ b1, float* __restrict__ h1,
    float* __restrict__ part)
{
    __shared__ __align__(16) short lds[16384];   // 32KB: hi [0,16KB), lo [16KB,32KB)
    const int t = threadIdx.x;
    const int mb = blockIdx.x * 64;

#pragma unroll
    for (int u = 0; u < 4; ++u) {
        int idx = u * 256 + t;
        int row = idx >> 4, sl = idx & 15;
        int gr = mb + row;
        short8 hv, lv;
#pragma unroll
        for (int e = 0; e < 8; ++e) { hv[e] = 0; lv[e] = 0; }
        if (gr < NNODES) {
            hv = *(const short8*)(Ahi + (size_t)gr * HID + sl * 8);
            lv = *(const short8*)(Alo + (size_t)gr * HID + sl * 8);
        }
        int byt = row * 256 + ((sl ^ (row & 7)) << 4);
        *(short8*)((char*)lds + byt) = hv;
        *(short8*)((char*)lds + 16384 + byt) = lv;
    }
    __syncthreads();

    const int lane = t & 63;
    const int wv = t >> 6;
    const int cl = lane & 15, g = lane >> 4, x = lane & 7;
    const int colbase = wv * 32;

    int aoff[4];
#pragma unroll
    for (int ks = 0; ks < 4; ++ks)
        aoff[ks] = cl * 256 + (((ks * 4 + g) ^ x) << 4);

    const unsigned short* wb_h0 = wh + (size_t)(colbase + cl) * HID + g * 8;
    const unsigned short* wb_h1 = wb_h0 + 16 * HID;
    const unsigned short* wb_l0 = wl + (size_t)(colbase + cl) * HID + g * 8;
    const unsigned short* wb_l1 = wb_l0 + 16 * HID;

    f32x4 acc[4][2];
#pragma unroll
    for (int rt = 0; rt < 4; ++rt) {
        acc[rt][0] = (f32x4){0.f, 0.f, 0.f, 0.f};
        acc[rt][1] = (f32x4){0.f, 0.f, 0.f, 0.f};
    }

#pragma unroll
    for (int ks = 0; ks < 4; ++ks) {
        short8 bh0 = *(const short8*)(wb_h0 + ks * 32);
        short8 bh1 = *(const short8*)(wb_h1 + ks * 32);
        short8 bl0 = *(const short8*)(wb_l0 + ks * 32);
        short8 bl1 = *(const short8*)(wb_l1 + ks * 32);
#pragma unroll
        for (int rt = 0; rt < 4; ++rt) {
            short8 ah = *(const short8*)((const char*)lds + (rt * 4096) + aoff[ks]);
            short8 al = *(const short8*)((const char*)lds + (16384 + rt * 4096) + aoff[ks]);
            acc[rt][0] = __builtin_amdgcn_mfma_f32_16x16x32_bf16(ah, bh0, acc[rt][0], 0, 0, 0);
            acc[rt][1] = __builtin_amdgcn_mfma_f32_16x16x32_bf16(ah, bh1, acc[rt][1], 0, 0, 0);
            acc[rt][0] = __builtin_amdgcn_mfma_f32_16x16x32_bf16(al, bh0, acc[rt][0], 0, 0, 0);
            acc[rt][1] = __builtin_amdgcn_mfma_f32_16x16x32_bf16(al, bh1, acc[rt][1], 0, 0, 0);
            acc[rt][0] = __builtin_amdgcn_mfma_f32_16x16x32_bf16(ah, bl0, acc[rt][0], 0, 0, 0);
            acc[rt][1] = __builtin_amdgcn_mfma_f32_16x16x32_bf16(ah, bl1, acc[rt][1], 0, 0, 0);
        }
    }

    float bj0 = b1[colbase + cl];
    float bj1 = b1[colbase + 16 + cl];
    float s0 = 0.f, q0 = 0.f, s1 = 0.f, q1 = 0.f;
#pragma unroll
    for (int rt = 0; rt < 4; ++rt) {
        int rbase = mb + rt * 16 + g * 4;
#pragma unroll
        for (int r = 0; r < 4; ++r) {
            int grow = rbase + r;
            if (grow < NNODES) {
                float o0 = acc[rt][0][r] + bj0;
                float o1 = acc[rt][1][r] + bj1;
                h1[(size_t)grow * HID + colbase + cl] = o0;
                h1[(size_t)grow * HID + colbase + 16 + cl] = o1;
                s0 += o0; q0 = fmaf(o0, o0, q0);
                s1 += o1; q1 = fmaf(o1, o1, q1);
            }
        }
    }
    __syncthreads();                 // LDS frag reads done; reuse as scratch
    float* red = (float*)lds;        // 1024 floats
    red[(colbase + cl) * 4 + g] = s0;
    red[(colbase + 16 + cl) * 4 + g] = s1;
    red[512 + (colbase + cl) * 4 + g] = q0;
    red[512 + (colbase + 16 + cl) * 4 + g] = q1;
    __syncthreads();
    {
        int stat = t >> 7, col = t & 127;
        const float* bp = red + stat * 512 + col * 4;
        part[(size_t)blockIdx.x * 256 + stat * 128 + col] = bp[0] + bp[1] + bp[2] + bp[3];
    }
}

// ================= MFMA GEMM2: Hout = leaky(leaky( leaky(BN(Ain)) @ W^T + b )) =================
template<int PRE, int POST>
__global__ __launch_bounds__(256) void gemm_mfma(
    const float* __restrict__ Ain, const float* __restrict__ scsh,
    const unsigned short* __restrict__ wh, const unsigned short* __restrict__ wl,
    const float* __restrict__ bias, float* __restrict__ Hout)
{
    __shared__ __align__(16) short lds[16384];   // 32KB
    const int t = threadIdx.x;
    const int mb = blockIdx.x * 64;

    const float4* sc4 = (const float4*)scsh;
    const float4* sh4 = (const float4*)(scsh + HID);

#pragma unroll
    for (int u = 0; u < 4; ++u) {
        int idx = u * 256 + t;
        int row = idx >> 4, sl = idx & 15;
        float4 v0 = make_float4(0.f, 0.f, 0.f, 0.f);
        float4 v1 = make_float4(0.f, 0.f, 0.f, 0.f);
        int gr = mb + row;
        if (gr < NNODES) {
            const float4* p = (const float4*)(Ain + (size_t)gr * HID + sl * 8);
            v0 = p[0]; v1 = p[1];
            if (PRE) {
                float4 c0 = sc4[sl * 2], c1 = sc4[sl * 2 + 1];
                float4 s0 = sh4[sl * 2], s1 = sh4[sl * 2 + 1];
                v0.x = leaky1(fmaf(v0.x, c0.x, s0.x));
                v0.y = leaky1(fmaf(v0.y, c0.y, s0.y));
                v0.z = leaky1(fmaf(v0.z, c0.z, s0.z));
                v0.w = leaky1(fmaf(v0.w, c0.w, s0.w));
                v1.x = leaky1(fmaf(v1.x, c1.x, s1.x));
                v1.y = leaky1(fmaf(v1.y, c1.y, s1.y));
                v1.z = leaky1(fmaf(v1.z, c1.z, s1.z));
                v1.w = leaky1(fmaf(v1.w, c1.w, s1.w));
            }
        }
        unsigned short h[8], l[8];
        splitf(v0.x, h[0], l[0]); splitf(v0.y, h[1], l[1]);
        splitf(v0.z, h[2], l[2]); splitf(v0.w, h[3], l[3]);
        splitf(v1.x, h[4], l[4]); splitf(v1.y, h[5], l[5]);
        splitf(v1.z, h[6], l[6]); splitf(v1.w, h[7], l[7]);
        short8 hv, lv;
#pragma unroll
        for (int e = 0; e < 8; ++e) { hv[e] = (short)h[e]; lv[e] = (short)l[e]; }
        int byt = row * 256 + ((sl ^ (row & 7)) << 4);
        *(short8*)((char*)lds + byt) = hv;
        *(short8*)((char*)lds + 16384 + byt) = lv;
    }
    __syncthreads();

    const int lane = t & 63;
    const int wv = t >> 6;
    const int cl = lane & 15, g = lane >> 4, x = lane & 7;
    const int colbase = wv * 32;

    int aoff[4];
#pragma unroll
    for (int ks = 0; ks < 4; ++ks)
        aoff[ks] = cl * 256 + (((ks * 4 + g) ^ x) << 4);

    const unsigned short* wb_h0 = wh + (size_t)(colbase + cl) * HID + g * 8;
    const unsigned short* wb_h1 = wb_h0 + 16 * HID;
    const unsigned short* wb_l0 = wl + (size_t)(colbase + cl) * HID + g * 8;
    const unsigned short* wb_l1 = wb_l0 + 16 * HID;

    f32x4 acc[4][2];
#pragma unroll
    for (int rt = 0; rt < 4; ++rt) {
        acc[rt][0] = (f32x4){0.f, 0.f, 0.f, 0.f};
        acc[rt][1] = (f32x4){0.f, 0.f, 0.f, 0.f};
    }

#pragma unroll
    for (int ks = 0; ks < 4; ++ks) {
        short8 bh0 = *(const short8*)(wb_h0 + ks * 32);
        short8 bh1 = *(const short8*)(wb_h1 + ks * 32);
        short8 bl0 = *(const short8*)(wb_l0 + ks * 32);
        short8 bl1 = *(const short8*)(wb_l1 + ks * 32);
#pragma unroll
        for (int rt = 0; rt < 4; ++rt) {
            short8 ah = *(const short8*)((const char*)lds + (rt * 4096) + aoff[ks]);
            short8 al = *(const short8*)((const char*)lds + (16384 + rt * 4096) + aoff[ks]);
            acc[rt][0] = __builtin_amdgcn_mfma_f32_16x16x32_bf16(ah, bh0, acc[rt][0], 0, 0, 0);
            acc[rt][1] = __builtin_amdgcn_mfma_f32_16x16x32_bf16(ah, bh1, acc[rt][1], 0, 0, 0);
            acc[rt][0] = __builtin_amdgcn_mfma_f32_16x16x32_bf16(al, bh0, acc[rt][0], 0, 0, 0);
            acc[rt][1] = __builtin_amdgcn_mfma_f32_16x16x32_bf16(al, bh1, acc[rt][1], 0, 0, 0);
            acc[rt][0] = __builtin_amdgcn_mfma_f32_16x16x32_bf16(ah, bl0, acc[rt][0], 0, 0, 0);
            acc[rt][1] = __builtin_amdgcn_mfma_f32_16x16x32_bf16(ah, bl1, acc[rt][1], 0, 0, 0);
        }
    }

    float bj0 = bias[colbase + cl];
    float bj1 = bias[colbase + 16 + cl];
#pragma unroll
    for (int rt = 0; rt < 4; ++rt) {
        int rbase = mb + rt * 16 + g * 4;
#pragma unroll
        for (int r = 0; r < 4; ++r) {
            int grow = rbase + r;
            if (grow < NNODES) {
                float o0 = acc[rt][0][r] + bj0;
                float o1 = acc[rt][1][r] + bj1;
                if (POST) { o0 = leaky1(leaky1(o0)); o1 = leaky1(leaky1(o1)); }
                Hout[(size_t)grow * HID + colbase + cl] = o0;
                Hout[(size_t)grow * HID + colbase + 16 + cl] = o1;
            }
        }
    }
}

// ================= global mean pool (batch sorted) =================
__global__ __launch_bounds__(256) void pool_kernel(
    const float* __restrict__ h, const int* __restrict__ batch,
    float* __restrict__ sums, float* __restrict__ cnt)
{
    int c = threadIdx.x & 127;
    int half = threadIdx.x >> 7;
    int base = blockIdx.x * 128 + half * 64;
    if (base >= NNODES) return;
    int end = base + 64; if (end > NNODES) end = NNODES;
    int g = batch[base];
    float acc = 0.0f, k = 0.0f;
    for (int n = base; n < end; ++n) {
        int gn = batch[n];
        if (gn != g) {
            atomicAdd(&sums[g * HID + c], acc);
            if (c == 0) atomicAdd(&cnt[g], k);
            acc = 0.0f; k = 0.0f; g = gn;
        }
        acc += h[(size_t)n * HID + c];
        k += 1.0f;
    }
    atomicAdd(&sums[g * HID + c], acc);
    if (c == 0) atomicAdd(&cnt[g], k);
}

// ================= reghead =================
__global__ __launch_bounds__(512) void reghead_kernel(
    const float* __restrict__ sums, const float* __restrict__ cnt,
    const float* __restrict__ wr, const float* __restrict__ br,
    const float* __restrict__ we, const float* __restrict__ be,
    float* __restrict__ out)
{
    __shared__ float pool[8 * HID];
    __shared__ float red[8][8];
    int g0 = blockIdx.x * 8;
    for (int i = threadIdx.x; i < 8 * HID; i += 512) {
        int g = g0 + (i >> 7);
        float c = cnt[g]; c = fmaxf(c, 1.0f);
        pool[i] = sums[g * HID + (i & 127)] / c;
    }
    __syncthreads();
    int j = threadIdx.x;
    float p[8];
#pragma unroll
    for (int g = 0; g < 8; ++g) p[g] = 0.0f;
    if (j < RHD) {
        float accs[8];
        float bjv = br[j];
#pragma unroll
        for (int g = 0; g < 8; ++g) accs[g] = bjv;
        const float4* wr4 = (const float4*)(wr + (size_t)j * HID);
        const float4* pool4 = (const float4*)pool;
        for (int k = 0; k < 32; ++k) {
            float4 w = wr4[k];
#pragma unroll
            for (int g = 0; g < 8; ++g) {
                float4 pv = pool4[g * 32 + k];
                accs[g] = fmaf(w.x, pv.x, accs[g]);
                accs[g] = fmaf(w.y, pv.y, accs[g]);
                accs[g] = fmaf(w.z, pv.z, accs[g]);
                accs[g] = fmaf(w.w, pv.w, accs[g]);
            }
        }
        float wej = we[j];
#pragma unroll
        for (int g = 0; g < 8; ++g) p[g] = leaky1(accs[g]) * wej;
    }
    int lane = threadIdx.x & 63, wid = threadIdx.x >> 6;
#pragma unroll
    for (int g = 0; g < 8; ++g) {
        float v = p[g];
        v += __shfl_down(v, 32); v += __shfl_down(v, 16); v += __shfl_down(v, 8);
        v += __shfl_down(v, 4);  v += __shfl_down(v, 2);  v += __shfl_down(v, 1);
        if (lane == 0) red[g][wid] = v;
    }
    __syncthreads();
    if (threadIdx.x < 8) {
        float sv = be[0];
#pragma unroll
        for (int w = 0; w < 8; ++w) sv += red[threadIdx.x][w];
        out[g0 + threadIdx.x] = sv;
    }
}

extern "C" void kernel_launch(void* const* d_in, const int* in_sizes, int n_in,
                              void* d_out, int out_size, void* d_ws, size_t ws_size,
                              hipStream_t stream)
{
    const float* x     = (const float*)d_in[0];
    const int*   ei    = (const int*)d_in[1];
    const int*   batch = (const int*)d_in[2];
    const float* ea    = (const float*)d_in[3];
    const float* ew0   = (const float*)d_in[4];
    const float* eb0   = (const float*)d_in[5];
    const float* w10   = (const float*)d_in[6];
    const float* b10   = (const float*)d_in[7];
    const float* g0v   = (const float*)d_in[8];
    const float* be0   = (const float*)d_in[9];
    const float* w20   = (const float*)d_in[10];
    const float* b20   = (const float*)d_in[11];
    const float* ewS   = (const float*)d_in[12];
    const float* ebS   = (const float*)d_in[13];
    const float* w1S   = (const float*)d_in[14];
    const float* b1S   = (const float*)d_in[15];
    const float* gS    = (const float*)d_in[16];
    const float* beS   = (const float*)d_in[17];
    const float* w2S   = (const float*)d_in[18];
    const float* b2S   = (const float*)d_in[19];
    const float* wr    = (const float*)d_in[20];
    const float* br    = (const float*)d_in[21];
    const float* we    = (const float*)d_in[22];
    const float* be_   = (const float*)d_in[23];

    float* ws    = (float*)d_ws;
    float* buf0  = ws;                                   // N*128 (h1)
    float* buf1  = buf0 + (size_t)NNODES * HID;          // N*128 (h)
    float* buf2  = buf1 + (size_t)NNODES * HID;          // N*128 (Ahi/Alo bf16 pair)
    unsigned short* Ahi = (unsigned short*)buf2;         // N*128 bf16
    unsigned short* Alo = Ahi + (size_t)NNODES * HID;    // N*128 bf16
    float* part  = buf2 + (size_t)NNODES * HID;          // GG*256
    float* scsh  = part + (size_t)GG * 256;              // 256
    float* sums  = scsh + 256;                           // 64*128
    float* cnt   = sums + NGRAPH * HID;                  // 64
    float* aggr2 = cnt + NGRAPH;                         // N*2
    float* eap   = aggr2 + (size_t)NNODES * 2;           // E*7
    int*   deg    = (int*)(eap + (size_t)NEDGES * 7);    // N
    int*   cursor = deg + NNODES;                        // N
    int*   bsum   = cursor + NNODES;                     // 512
    int*   rp     = bsum + 512;                          // N+1
    int*   eid    = rp + NNODES + 1;                     // E
    int*   srcp   = eid + NEDGES;                        // E
    unsigned short* whA = (unsigned short*)(srcp + NEDGES);  // 7*16384
    unsigned short* wlA = whA + 7 * 16384;                   // 7*16384
    float* out   = (float*)d_out;

    // ---- CSR build (deterministic; once per launch) ----
    hipMemsetAsync(deg, 0, (size_t)NNODES * sizeof(int), stream);
    hist_kernel<<<EB, 256, 0, stream>>>(ei, deg);
    scan_blk<<<NB, 256, 0, stream>>>(deg, rp, bsum);
    scan_bsum<<<1, 512, 0, stream>>>(bsum, NB);
    finalize_rp<<<NB, 256, 0, stream>>>(deg, bsum, rp, cursor);
    scatter_kernel<<<EB, 256, 0, stream>>>(ei, cursor, eid);
    seg_sort<<<NB, 256, 0, stream>>>(rp, eid);
    permute_kernel<<<EB, 256, 0, stream>>>(eid, ei, ea, srcp, eap);

    // ---- weight split: one launch ----
    wsplit_all<<<448, 256, 0, stream>>>(w20, w1S, w2S, whA, wlA);

    // ---- layer 0: h1 -> buf0, h -> buf1 ----
    aggregate0_kernel<<<NB, 256, 0, stream>>>(x, rp, srcp, eap, ew0, eb0, aggr2);
    gemm1_l0_kernel<<<NB, 256, 0, stream>>>(aggr2, w10, b10, buf0);
    bn_stats_part<<<NB, 256, 0, stream>>>(buf0, part);
    bn_finalize<<<HID, 256, 0, stream>>>(part, NB, g0v, be0, scsh);
    gemm_mfma<1, 1><<<GG, 256, 0, stream>>>(buf0, scsh, whA, wlA, b20, buf1);

    // ---- hidden layers: h stays in buf1; A split pair in buf2; h1 in buf0 ----
    for (int i = 0; i < 3; ++i) {
        aggregate_kernel<<<NNODES / 32, 256, 0, stream>>>(buf1, rp, srcp, eap,
            ewS + (size_t)i * HID * 7, ebS + (size_t)i * HID, Ahi, Alo);
        gemm1_lds<<<GG, 256, 0, stream>>>(Ahi, Alo,
            whA + (size_t)(1 + i) * 16384, wlA + (size_t)(1 + i) * 16384,
            b1S + (size_t)i * HID, buf0, part);                 // h1 -> buf0 + BN partials
        bn_finalize<<<HID, 256, 0, stream>>>(part, GG,
            gS + (size_t)i * HID, beS + (size_t)i * HID, scsh);
        gemm_mfma<1, 1><<<GG, 256, 0, stream>>>(buf0, scsh,
            whA + (size_t)(4 + i) * 16384, wlA + (size_t)(4 + i) * 16384,
            b2S + (size_t)i * HID, buf1);                       // h -> buf1
    }

    // ---- pooling + reghead ----
    hipMemsetAsync(sums, 0, (size_t)(NGRAPH * HID + NGRAPH) * sizeof(float), stream);
    pool_kernel<<<(NNODES + 127) / 128, 256, 0, stream>>>(buf1, batch, sums, cnt);
    reghead_kernel<<<NGRAPH / 8, 512, 0, stream>>>(sums, cnt, wr, br, we, be_, out);
}